// Round 7
// baseline (6310.800 us; speedup 1.0000x reference)
//
#include <hip/hip_runtime.h>
#include <cstdint>
#include <cstddef>

#define VSZ 32000
#define ED  512
#define HD  512
#define SQ  128
#define BA  64
#define INW 1024
#define NG  1536

typedef __attribute__((ext_vector_type(8))) short sh8;
typedef __attribute__((ext_vector_type(4))) float f32x4;
typedef _Float16 half8 __attribute__((ext_vector_type(8)));

__device__ inline unsigned short f2bf(float f) {
  unsigned int u = __float_as_uint(f);
  u += 0x7fffu + ((u >> 16) & 1u);
  return (unsigned short)(u >> 16);
}

// ---------------- pre-projection: XG[m, 0:1536] = emb[x[m]] @ {Wr,Wz,Wh}[:, :512]^T + bias ----
__global__ __launch_bounds__(256) void proj_kernel(
    const int* __restrict__ x, const float* __restrict__ emb,
    const float* __restrict__ Wr, const float* __restrict__ Br,
    const float* __restrict__ Wz, const float* __restrict__ Bz,
    const float* __restrict__ Wh, const float* __restrict__ Bh,
    float* __restrict__ XG)
{
  __shared__ float As[32][68];
  __shared__ float Bs[32][68];
  const int tid = threadIdx.x;
  const int bx = blockIdx.x;   // N tile: 0..23
  const int by = blockIdx.y;   // M tile: 0..127
  const int tx = tid & 15, ty = tid >> 4;
  float acc[4][4] = {{0.f}};

  for (int k0 = 0; k0 < ED; k0 += 32) {
    #pragma unroll
    for (int it = 0; it < 2; ++it) {
      const int s   = tid + it * 256;
      const int row = s >> 3;
      const int c4  = (s & 7) << 2;
      {
        const int m    = by * 64 + row;
        const int vrow = x[m];
        const float4 v = *(const float4*)(emb + (size_t)vrow * ED + k0 + c4);
        As[c4+0][row] = v.x; As[c4+1][row] = v.y; As[c4+2][row] = v.z; As[c4+3][row] = v.w;
      }
      {
        const int j  = bx * 64 + row;
        const int g  = j >> 9, jj = j & 511;
        const float* wrow = (g == 0 ? Wr : (g == 1 ? Wz : Wh)) + (size_t)jj * INW;
        const float4 v = *(const float4*)(wrow + k0 + c4);
        Bs[c4+0][row] = v.x; Bs[c4+1][row] = v.y; Bs[c4+2][row] = v.z; Bs[c4+3][row] = v.w;
      }
    }
    __syncthreads();
    #pragma unroll
    for (int k = 0; k < 32; ++k) {
      const float4 a4 = *(const float4*)&As[k][ty << 2];
      const float4 b4 = *(const float4*)&Bs[k][tx << 2];
      const float av[4] = {a4.x, a4.y, a4.z, a4.w};
      const float bv[4] = {b4.x, b4.y, b4.z, b4.w};
      #pragma unroll
      for (int i = 0; i < 4; ++i)
        #pragma unroll
        for (int j = 0; j < 4; ++j)
          acc[i][j] += av[i] * bv[j];
    }
    __syncthreads();
  }
  #pragma unroll
  for (int j = 0; j < 4; ++j) {
    const int jc = bx * 64 + (tx << 2) + j;
    const int g = jc >> 9, jj = jc & 511;
    const float bias = (g == 0 ? Br : (g == 1 ? Bz : Bh))[jj];
    #pragma unroll
    for (int i = 0; i < 4; ++i) {
      const int m = by * 64 + (ty << 2) + i;
      XG[(size_t)m * NG + jc] = acc[i][j] + bias;
    }
  }
}

// ---------------- weight pack: recurrent halves -> fp16 MFMA B-fragment order -----------------
// pack[((g*32+nt)*16+kt)*512 + lane*8 + j] = Wg[nt*16 + (lane&15)][512 + kt*32 + (lane>>4)*8 + j]
__global__ __launch_bounds__(64) void wpack_kernel(
    const float* __restrict__ Wr, const float* __restrict__ Wz, const float* __restrict__ Wh,
    _Float16* __restrict__ pack)
{
  const int f = blockIdx.x;          // 0..1535
  const int l = threadIdx.x;         // 0..63
  const int g = f >> 9, rem = f & 511, nt = rem >> 4, kt = rem & 15;
  const float* Wsrc = (g == 0 ? Wr : (g == 1 ? Wz : Wh));
  const float* src = Wsrc + (size_t)(nt * 16 + (l & 15)) * INW + ED + kt * 32 + (l >> 4) * 8;
  const float4 a = *(const float4*)src;
  const float4 b = *(const float4*)(src + 4);
  half8 w;
  w[0]=(_Float16)a.x; w[1]=(_Float16)a.y; w[2]=(_Float16)a.z; w[3]=(_Float16)a.w;
  w[4]=(_Float16)b.x; w[5]=(_Float16)b.y; w[6]=(_Float16)b.z; w[7]=(_Float16)b.w;
  *(half8*)(pack + (size_t)f * 512 + (size_t)l * 8) = w;
}

// ---------------- batch-parallel GRU recurrence: 8 WGs x 512 thr, all state in LDS ------------
// WG owns 8 batch rows (padded to M=16). Phase A: 8 waves x 8 ntiles of [r(512)|z(512)].
// Phase B: 8 waves x 4 ntiles of h_cand(512). Weights streamed from L2 (packed fp16 frags).
// No grid sync; 2 __syncthreads per step.
__global__ __launch_bounds__(512) void recur_kernel(
    const float* __restrict__ XG,       // [8192][1536]
    const _Float16* __restrict__ Wpack, // [3][32][16][64][8]
    unsigned short* __restrict__ Habf,  // [8192][512] bf16
    float* __restrict__ outT)           // [512][64]  (hT.T)
{
  __shared__ float    xg_rz[8][1024];   // 32 KiB  XG r|z parts, this step
  __shared__ float    xg_h [8][512];    // 16 KiB  XG h-cand part, this step
  __shared__ float    h32s [8][512];    // 16 KiB  fp32 h state
  __shared__ float    z32s [8][512];    // 16 KiB  z gate
  __shared__ _Float16 hFs  [16][528];   // 16.5 KiB fp16 h (A-operand, padded rows zero)
  __shared__ _Float16 uFs  [16][528];   // 16.5 KiB fp16 r*h (A-operand)

  const int tid = threadIdx.x, wg = blockIdx.x;
  const int wv = tid >> 6, lane = tid & 63;
  const int l15 = lane & 15, lhi = lane >> 4;
  const int rowbase = wg * 8;

  // zero state (h=0; pad rows of A-operands must be clean)
  for (int i = tid; i < 8 * 512; i += 512) ((float*)h32s)[i] = 0.0f;
  for (int i = tid; i < 16 * 528; i += 512) {
    ((_Float16*)hFs)[i] = (_Float16)0.0f;
    ((_Float16*)uFs)[i] = (_Float16)0.0f;
  }
  // stage XG r,z for t=0
  #pragma unroll
  for (int i = 0; i < 4; ++i) {
    const int idx = tid + i * 512;
    const int r = idx >> 8, c = (idx & 255) << 2;
    const float4 v = *(const float4*)(XG + (size_t)(rowbase + r) * NG + c);
    *(float4*)&xg_rz[r][c] = v;
  }
  __syncthreads();

  const int gA   = (wv < 4) ? 0 : 1;      // waves 0-3: r, waves 4-7: z
  const int cbA  = (wv & 3) * 128;        // phase-A column base within gate
  const _Float16* packA = Wpack + (size_t)((gA * 32 + (wv & 3) * 8) * 16) * 512;
  const _Float16* packB = Wpack + (size_t)((2 * 32 + wv * 4) * 16) * 512;

  for (int t = 0; t < SQ; ++t) {
    // ---- stage XG h-part for step t (consumed in epilogue B, after sync1) ----
    #pragma unroll
    for (int i = 0; i < 2; ++i) {
      const int idx = tid + i * 512;
      const int r = idx >> 7, c = (idx & 127) << 2;
      const float4 v = *(const float4*)(XG + (size_t)(t * BA + rowbase + r) * NG + 1024 + c);
      *(float4*)&xg_h[r][c] = v;
    }
    // ---- phase A GEMM: h @ W{r|z}h^T  (8 ntiles x 16 kt, B prefetched 1 kt ahead) ----
    f32x4 acc[8] = {};
    half8 af[2], bf[2][8];
    af[0] = *(const half8*)&hFs[l15][lhi * 8];
    #pragma unroll
    for (int nt = 0; nt < 8; ++nt)
      bf[0][nt] = *(const half8*)(packA + (size_t)(nt * 16) * 512 + lane * 8);
    #pragma unroll
    for (int kt = 0; kt < 16; ++kt) {
      const int cur = kt & 1, nxt = cur ^ 1;
      if (kt < 15) {
        af[nxt] = *(const half8*)&hFs[l15][(kt + 1) * 32 + lhi * 8];
        #pragma unroll
        for (int nt = 0; nt < 8; ++nt)
          bf[nxt][nt] = *(const half8*)(packA + (size_t)(nt * 16 + kt + 1) * 512 + lane * 8);
      }
      #pragma unroll
      for (int nt = 0; nt < 8; ++nt)
        acc[nt] = __builtin_amdgcn_mfma_f32_16x16x32_f16(af[cur], bf[cur][nt], acc[nt], 0, 0, 0);
    }
    // ---- epilogue A: sigmoid; r-waves write uF=r*h, z-waves write z ----
    if (lhi < 2) {
      #pragma unroll
      for (int nt = 0; nt < 8; ++nt) {
        const int col = cbA + nt * 16 + l15;
        #pragma unroll
        for (int q = 0; q < 4; ++q) {
          const int row = lhi * 4 + q;
          if (gA == 0) {
            const float pre = acc[nt][q] + xg_rz[row][col];
            const float r = 1.0f / (1.0f + __expf(-pre));
            uFs[row][col] = (_Float16)(r * h32s[row][col]);
          } else {
            const float pre = acc[nt][q] + xg_rz[row][512 + col];
            z32s[row][col] = 1.0f / (1.0f + __expf(-pre));
          }
        }
      }
    }
    __syncthreads();

    // ---- stage XG r,z for t+1 (xg_rz dead after epilogue A) ----
    if (t + 1 < SQ) {
      #pragma unroll
      for (int i = 0; i < 4; ++i) {
        const int idx = tid + i * 512;
        const int r = idx >> 8, c = (idx & 255) << 2;
        const float4 v = *(const float4*)(XG + (size_t)((t + 1) * BA + rowbase + r) * NG + c);
        *(float4*)&xg_rz[r][c] = v;
      }
    }
    // ---- phase B GEMM: u @ Whh^T  (4 ntiles x 16 kt) ----
    f32x4 accB[4] = {};
    half8 afB[2], bfB[2][4];
    afB[0] = *(const half8*)&uFs[l15][lhi * 8];
    #pragma unroll
    for (int nt = 0; nt < 4; ++nt)
      bfB[0][nt] = *(const half8*)(packB + (size_t)(nt * 16) * 512 + lane * 8);
    #pragma unroll
    for (int kt = 0; kt < 16; ++kt) {
      const int cur = kt & 1, nxt = cur ^ 1;
      if (kt < 15) {
        afB[nxt] = *(const half8*)&uFs[l15][(kt + 1) * 32 + lhi * 8];
        #pragma unroll
        for (int nt = 0; nt < 4; ++nt)
          bfB[nxt][nt] = *(const half8*)(packB + (size_t)(nt * 16 + kt + 1) * 512 + lane * 8);
      }
      #pragma unroll
      for (int nt = 0; nt < 4; ++nt)
        accB[nt] = __builtin_amdgcn_mfma_f32_16x16x32_f16(afB[cur], bfB[cur][nt], accB[nt], 0, 0, 0);
    }
    // ---- epilogue B: tanh + combine; update h32/hF, emit Habf ----
    if (lhi < 2) {
      #pragma unroll
      for (int nt = 0; nt < 4; ++nt) {
        const int col = wv * 64 + nt * 16 + l15;
        #pragma unroll
        for (int q = 0; q < 4; ++q) {
          const int row = lhi * 4 + q;
          const float pre = accB[nt][q] + xg_h[row][col];
          const float e  = __expf(2.0f * pre);          // tanh, inf-safe
          const float hc = 1.0f - 2.0f / (e + 1.0f);
          const float z  = z32s[row][col];
          const float ho = h32s[row][col];
          const float hn = z * ho + (1.0f - z) * hc;
          h32s[row][col] = hn;
          hFs[row][col]  = (_Float16)hn;
          Habf[(size_t)(t * BA + rowbase + row) * HD + col] = f2bf(hn);
          if (t == SQ - 1) outT[col * BA + rowbase + row] = hn;
        }
      }
    }
    __syncthreads();
  }
}

// ---------------- final output GEMM: Y = Habf @ W^T + b  (bf16 MFMA, fp32 out) ----------------
__global__ __launch_bounds__(256) void out_gemm_kernel(
    const unsigned short* __restrict__ A,  // 8192 x 512 bf16
    const float* __restrict__ Bw,          // 32000 x 512 f32
    const float* __restrict__ bias,        // 32000
    float* __restrict__ Y)                 // 8192 x 32000
{
  __shared__ unsigned short As[128 * 32];
  __shared__ unsigned short Bs[128 * 32];
  const int bid = blockIdx.x;
  const int tn = bid % 250, tm = bid / 250;
  const int tid = threadIdx.x;
  const int wave = tid >> 6, lane = tid & 63;
  const int wm = wave >> 1, wn = wave & 1;
  const int l15 = lane & 15, lhi = lane >> 4;
  f32x4 acc[4][4] = {};

  for (int k0 = 0; k0 < 512; k0 += 32) {
    #pragma unroll
    for (int it = 0; it < 2; ++it) {
      const int ss  = tid + it * 256;
      const int row = ss >> 2;
      const int c8  = (ss & 3) << 3;
      *(uint4*)(As + row * 32 + c8) =
          *(const uint4*)(A + (size_t)(tm * 128 + row) * 512 + k0 + c8);
      const float4 b0 = *(const float4*)(Bw + (size_t)(tn * 128 + row) * 512 + k0 + c8);
      const float4 b1 = *(const float4*)(Bw + (size_t)(tn * 128 + row) * 512 + k0 + c8 + 4);
      union { unsigned short h[8]; uint4 u; } cv;
      cv.h[0] = f2bf(b0.x); cv.h[1] = f2bf(b0.y); cv.h[2] = f2bf(b0.z); cv.h[3] = f2bf(b0.w);
      cv.h[4] = f2bf(b1.x); cv.h[5] = f2bf(b1.y); cv.h[6] = f2bf(b1.z); cv.h[7] = f2bf(b1.w);
      *(uint4*)(Bs + row * 32 + c8) = cv.u;
    }
    __syncthreads();
    sh8 af[4], bfr[4];
    #pragma unroll
    for (int mi = 0; mi < 4; ++mi)
      af[mi] = *(const sh8*)(As + (wm * 64 + mi * 16 + l15) * 32 + lhi * 8);
    #pragma unroll
    for (int ni = 0; ni < 4; ++ni)
      bfr[ni] = *(const sh8*)(Bs + (wn * 64 + ni * 16 + l15) * 32 + lhi * 8);
    #pragma unroll
    for (int mi = 0; mi < 4; ++mi)
      #pragma unroll
      for (int ni = 0; ni < 4; ++ni)
        acc[mi][ni] = __builtin_amdgcn_mfma_f32_16x16x32_bf16(af[mi], bfr[ni], acc[mi][ni], 0, 0, 0);
    __syncthreads();
  }

  #pragma unroll
  for (int ni = 0; ni < 4; ++ni) {
    const int col = tn * 128 + wn * 64 + ni * 16 + l15;
    const float bv = bias[col];
    #pragma unroll
    for (int mi = 0; mi < 4; ++mi) {
      const int row0 = tm * 128 + wm * 64 + mi * 16 + lhi * 4;
      #pragma unroll
      for (int q = 0; q < 4; ++q)
        Y[(size_t)(row0 + q) * VSZ + col] = acc[mi][ni][q] + bv;
    }
  }
}

extern "C" void kernel_launch(void* const* d_in, const int* in_sizes, int n_in,
                              void* d_out, int out_size, void* d_ws, size_t ws_size,
                              hipStream_t stream)
{
  const int*   x   = (const int*)  d_in[0];
  const float* emb = (const float*)d_in[1];
  const float* Wr  = (const float*)d_in[2];
  const float* Br  = (const float*)d_in[3];
  const float* Wz  = (const float*)d_in[4];
  const float* Bz  = (const float*)d_in[5];
  const float* Wh  = (const float*)d_in[6];
  const float* Bh  = (const float*)d_in[7];
  const float* W   = (const float*)d_in[8];
  const float* bo  = (const float*)d_in[9];
  float* out = (float*)d_out;

  unsigned short* Habf = (unsigned short*)d_ws;   // 8 MiB bf16 h history

  // Overlays in d_out (dead before out_gemm writes Y):
  float*     XG    = out;                          // [8192][1536]  pre-projection
  _Float16*  Wpack = (_Float16*)(out + 12582912);  // 1.5 MiB packed fp16 weight frags
  float*     outT  = out + 262144000ll;            // hT.T region

  proj_kernel<<<dim3(24, 128), 256, 0, stream>>>(x, emb, Wr, Br, Wz, Bz, Wh, Bh, XG);
  wpack_kernel<<<1536, 64, 0, stream>>>(Wr, Wz, Wh, Wpack);
  recur_kernel<<<8, 512, 0, stream>>>(XG, Wpack, Habf, outT);
  out_gemm_kernel<<<16000, 256, 0, stream>>>(Habf, W, bo, out);
}

// Round 9
// 2402.540 us; speedup vs baseline: 2.6267x; 2.6267x over previous
//
#include <hip/hip_runtime.h>
#include <cstdint>
#include <cstddef>

#define VSZ 32000
#define ED  512
#define HD  512
#define SQ  128
#define BA  64
#define INW 1024
#define NG  1536
#define NWG 32
#define FLG 32   // flag stride in dwords (one 128B line per WG)

typedef __attribute__((ext_vector_type(8))) short sh8;
typedef __attribute__((ext_vector_type(4))) float f32x4;
typedef _Float16 half8 __attribute__((ext_vector_type(8)));
typedef unsigned u32x4 __attribute__((ext_vector_type(4)));

__device__ inline unsigned short f2bf(float f) {
  unsigned int u = __float_as_uint(f);
  u += 0x7fffu + ((u >> 16) & 1u);
  return (unsigned short)(u >> 16);
}

// Device-scope 16B load (bypass L1+L2, read L3 coherence point). Pipelined:
// caller issues a burst, then ONE s_waitcnt vmcnt(0) + sched_barrier(0).
__device__ __forceinline__ half8 ld_h8_dev(const _Float16* p) {
  u32x4 r;
  asm volatile("global_load_dwordx4 %0, %1, off sc0 sc1" : "=v"(r) : "v"(p));
  return __builtin_bit_cast(half8, r);
}

__device__ __forceinline__ void st_u32_dev(unsigned* p, unsigned v) {
  asm volatile("global_store_dword %0, %1, off sc0 sc1" :: "v"(p), "v"(v) : "memory");
}

__device__ __forceinline__ unsigned ld_u32_dev(const unsigned* p) {
  unsigned r;
  asm volatile("global_load_dword %0, %1, off sc0 sc1" : "=v"(r) : "v"(p));
  asm volatile("s_waitcnt vmcnt(0)" ::: "memory");
  __builtin_amdgcn_sched_barrier(0);
  return r;
}

// Contention-free grid barrier: per-WG flag (one L3 line each) + all-lane poll.
// vmcnt(0)+__syncthreads drains this WG's device-scope data stores first.
__device__ __forceinline__ void gridbar(unsigned* flags, unsigned epoch, int wg) {
  asm volatile("s_waitcnt vmcnt(0)" ::: "memory");
  __syncthreads();
  if (threadIdx.x < 64) {
    const int lane = threadIdx.x;
    if (lane == 0) st_u32_dev(flags + wg * FLG, epoch);
    const unsigned* fp = flags + (lane & (NWG - 1)) * FLG;
    unsigned v = ld_u32_dev(fp);
    while (!__all((int)(v >= epoch))) {
      __builtin_amdgcn_s_sleep(1);
      v = ld_u32_dev(fp);
    }
  }
  __syncthreads();
}

// ---------------- pre-projection: XG[m, 0:1536] = emb[x[m]] @ {Wr,Wz,Wh}[:, :512]^T + bias ----
__global__ __launch_bounds__(256) void proj_kernel(
    const int* __restrict__ x, const float* __restrict__ emb,
    const float* __restrict__ Wr, const float* __restrict__ Br,
    const float* __restrict__ Wz, const float* __restrict__ Bz,
    const float* __restrict__ Wh, const float* __restrict__ Bh,
    float* __restrict__ XG)
{
  __shared__ float As[32][68];
  __shared__ float Bs[32][68];
  const int tid = threadIdx.x;
  const int bx = blockIdx.x;   // N tile: 0..23
  const int by = blockIdx.y;   // M tile: 0..127
  const int tx = tid & 15, ty = tid >> 4;
  float acc[4][4] = {{0.f}};

  for (int k0 = 0; k0 < ED; k0 += 32) {
    #pragma unroll
    for (int it = 0; it < 2; ++it) {
      const int s   = tid + it * 256;
      const int row = s >> 3;
      const int c4  = (s & 7) << 2;
      {
        const int m    = by * 64 + row;
        const int vrow = x[m];
        const float4 v = *(const float4*)(emb + (size_t)vrow * ED + k0 + c4);
        As[c4+0][row] = v.x; As[c4+1][row] = v.y; As[c4+2][row] = v.z; As[c4+3][row] = v.w;
      }
      {
        const int j  = bx * 64 + row;
        const int g  = j >> 9, jj = j & 511;
        const float* wrow = (g == 0 ? Wr : (g == 1 ? Wz : Wh)) + (size_t)jj * INW;
        const float4 v = *(const float4*)(wrow + k0 + c4);
        Bs[c4+0][row] = v.x; Bs[c4+1][row] = v.y; Bs[c4+2][row] = v.z; Bs[c4+3][row] = v.w;
      }
    }
    __syncthreads();
    #pragma unroll
    for (int k = 0; k < 32; ++k) {
      const float4 a4 = *(const float4*)&As[k][ty << 2];
      const float4 b4 = *(const float4*)&Bs[k][tx << 2];
      const float av[4] = {a4.x, a4.y, a4.z, a4.w};
      const float bv[4] = {b4.x, b4.y, b4.z, b4.w};
      #pragma unroll
      for (int i = 0; i < 4; ++i)
        #pragma unroll
        for (int j = 0; j < 4; ++j)
          acc[i][j] += av[i] * bv[j];
    }
    __syncthreads();
  }
  #pragma unroll
  for (int j = 0; j < 4; ++j) {
    const int jc = bx * 64 + (tx << 2) + j;
    const int g = jc >> 9, jj = jc & 511;
    const float bias = (g == 0 ? Br : (g == 1 ? Bz : Bh))[jj];
    #pragma unroll
    for (int i = 0; i < 4; ++i) {
      const int m = by * 64 + (ty << 2) + i;
      XG[(size_t)m * NG + jc] = acc[i][j] + bias;
    }
  }
}

// ---------------- persistent GRU recurrence (MFMA, weights in VGPRs, device-scope exchange) ---
// 32 WGs x 256 thr (4 waves). WG w owns columns w*16..w*16+15 of r, z AND h_cand.
// Cross-WG h/u exchange via plain asm sc0+sc1 (device-scope) loads/stores, burst-issued.
__global__ __launch_bounds__(256) void recur_kernel(
    const float* __restrict__ XG,     // [8192][1536]
    const float* __restrict__ Wr, const float* __restrict__ Wz, const float* __restrict__ Wh,
    float* __restrict__ h32,          // [64][512] fp32   (WG-private cols)
    float* __restrict__ z32,          // [64][512] fp32   (WG-private cols)
    _Float16* __restrict__ hF,        // [64][512] fp16   (device-coherent)
    _Float16* __restrict__ uF,        // [64][512] fp16   (device-coherent, r*h)
    unsigned short* __restrict__ Habf,// [8192][512] bf16
    float* __restrict__ outT,         // [512][64]  (hT.T)
    unsigned* __restrict__ flags)
{
  const int tid = threadIdx.x, wg = blockIdx.x;
  const int wv = tid >> 6, lane = tid & 63;
  const int l15 = lane & 15, lhi = lane >> 4;
  const int mrow = wv * 16 + l15;          // A-fragment row (batch)
  const int col  = wg * 16 + l15;          // owned column (same for r, z, h_cand)

  // ---- load weight B-fragments into registers (fp16), once ----
  half8 wfR[16], wfZ[16], wfH[16];
  {
    const float* WR = Wr + (size_t)col * INW + ED + lhi * 8;
    const float* WZ = Wz + (size_t)col * INW + ED + lhi * 8;
    const float* WH = Wh + (size_t)col * INW + ED + lhi * 8;
    #pragma unroll
    for (int s = 0; s < 16; ++s) {
      float4 a, b; half8 w;
      a = *(const float4*)(WR + s * 32); b = *(const float4*)(WR + s * 32 + 4);
      w[0]=(_Float16)a.x; w[1]=(_Float16)a.y; w[2]=(_Float16)a.z; w[3]=(_Float16)a.w;
      w[4]=(_Float16)b.x; w[5]=(_Float16)b.y; w[6]=(_Float16)b.z; w[7]=(_Float16)b.w;
      wfR[s] = w;
      a = *(const float4*)(WZ + s * 32); b = *(const float4*)(WZ + s * 32 + 4);
      w[0]=(_Float16)a.x; w[1]=(_Float16)a.y; w[2]=(_Float16)a.z; w[3]=(_Float16)a.w;
      w[4]=(_Float16)b.x; w[5]=(_Float16)b.y; w[6]=(_Float16)b.z; w[7]=(_Float16)b.w;
      wfZ[s] = w;
      a = *(const float4*)(WH + s * 32); b = *(const float4*)(WH + s * 32 + 4);
      w[0]=(_Float16)a.x; w[1]=(_Float16)a.y; w[2]=(_Float16)a.z; w[3]=(_Float16)a.w;
      w[4]=(_Float16)b.x; w[5]=(_Float16)b.y; w[6]=(_Float16)b.z; w[7]=(_Float16)b.w;
      wfH[s] = w;
    }
  }

  // XG values for step 0 (plain cached loads; later steps prefetched inside phase A)
  float xgR[4], xgZ[4], xgH[4];
  #pragma unroll
  for (int q = 0; q < 4; ++q) {
    const int b = wv * 16 + lhi * 4 + q;
    const float* xp = XG + (size_t)b * NG + col;
    xgR[q] = xp[0]; xgZ[q] = xp[512]; xgH[q] = xp[1024];
  }

  unsigned epoch = 0;
  for (int t = 0; t < SQ; ++t) {
    float nR[4] = {0,0,0,0}, nZ[4] = {0,0,0,0}, nH[4] = {0,0,0,0};
    // ---- phase A: preR/preZ = h @ W{r,z}h^T ; sigmoid -> uF (dev), z32 (private) ----
    {
      half8 ha[16];
      #pragma unroll
      for (int s = 0; s < 16; ++s)
        ha[s] = ld_h8_dev(hF + (size_t)mrow * HD + s * 32 + lhi * 8);
      asm volatile("s_waitcnt vmcnt(0)" ::: "memory");
      __builtin_amdgcn_sched_barrier(0);

      // prefetch next step's XG now: overlaps A-MFMA + barrier + B-operand loads
      if (t + 1 < SQ) {
        #pragma unroll
        for (int q = 0; q < 4; ++q) {
          const int b = wv * 16 + lhi * 4 + q;
          const float* xp = XG + (size_t)(t + 1) * BA * NG + (size_t)b * NG + col;
          nR[q] = xp[0]; nZ[q] = xp[512]; nH[q] = xp[1024];
        }
      }

      f32x4 accR = {}, accZ = {};
      #pragma unroll
      for (int s = 0; s < 16; ++s) {
        accR = __builtin_amdgcn_mfma_f32_16x16x32_f16(ha[s], wfR[s], accR, 0, 0, 0);
        accZ = __builtin_amdgcn_mfma_f32_16x16x32_f16(ha[s], wfZ[s], accZ, 0, 0, 0);
      }
      #pragma unroll
      for (int q = 0; q < 4; ++q) {
        const int b = wv * 16 + lhi * 4 + q;
        const float preR = accR[q] + xgR[q];
        const float r  = 1.0f / (1.0f + __expf(-preR));
        const float uv = r * h32[(size_t)b * HD + col];
        const _Float16 uh = (_Float16)uv;
        const unsigned short ub = __builtin_bit_cast(unsigned short, uh);
        const unsigned short ob = (unsigned short)__shfl_xor((int)ub, 1);
        if (!(l15 & 1)) {
          const unsigned wrd = (unsigned)ub | ((unsigned)ob << 16);
          st_u32_dev((unsigned*)(uF + (size_t)b * HD + col), wrd);
        }
        const float preZ = accZ[q] + xgZ[q];
        z32[(size_t)b * HD + col] = 1.0f / (1.0f + __expf(-preZ));
      }
    }
    ++epoch; gridbar(flags, epoch, wg);

    // ---- phase B: pre = u @ Whh^T ; tanh + combine -> h32 (private), hF (dev) ----
    {
      half8 ua[16];
      #pragma unroll
      for (int s = 0; s < 16; ++s)
        ua[s] = ld_h8_dev(uF + (size_t)mrow * HD + s * 32 + lhi * 8);
      asm volatile("s_waitcnt vmcnt(0)" ::: "memory");
      __builtin_amdgcn_sched_barrier(0);
      f32x4 acc = {};
      #pragma unroll
      for (int s = 0; s < 16; ++s)
        acc = __builtin_amdgcn_mfma_f32_16x16x32_f16(ua[s], wfH[s], acc, 0, 0, 0);

      #pragma unroll
      for (int q = 0; q < 4; ++q) {
        const int b = wv * 16 + lhi * 4 + q;
        const float pre = acc[q] + xgH[q];
        const float e  = __expf(2.0f * pre);          // tanh, inf-safe
        const float hc = 1.0f - 2.0f / (e + 1.0f);
        const float z  = z32[(size_t)b * HD + col];
        const float ho = h32[(size_t)b * HD + col];
        const float hn = z * ho + (1.0f - z) * hc;
        h32[(size_t)b * HD + col] = hn;
        Habf[(size_t)(t * BA + b) * HD + col] = f2bf(hn);
        const _Float16 hh = (_Float16)hn;
        const unsigned short hb = __builtin_bit_cast(unsigned short, hh);
        const unsigned short hob = (unsigned short)__shfl_xor((int)hb, 1);
        if (!(l15 & 1)) {
          const unsigned wrd = (unsigned)hb | ((unsigned)hob << 16);
          st_u32_dev((unsigned*)(hF + (size_t)b * HD + col), wrd);
        }
        if (t == SQ - 1) outT[col * BA + b] = hn;
      }
      #pragma unroll
      for (int q = 0; q < 4; ++q) { xgR[q] = nR[q]; xgZ[q] = nZ[q]; xgH[q] = nH[q]; }
    }
    ++epoch; gridbar(flags, epoch, wg);
  }
}

// ---------------- final output GEMM: Y = Habf @ W^T + b  (bf16 MFMA, fp32 out) ----------------
__global__ __launch_bounds__(256) void out_gemm_kernel(
    const unsigned short* __restrict__ A,  // 8192 x 512 bf16
    const float* __restrict__ Bw,          // 32000 x 512 f32
    const float* __restrict__ bias,        // 32000
    float* __restrict__ Y)                 // 8192 x 32000
{
  __shared__ unsigned short As[128 * 32];
  __shared__ unsigned short Bs[128 * 32];
  const int bid = blockIdx.x;
  const int tn = bid % 250, tm = bid / 250;
  const int tid = threadIdx.x;
  const int wave = tid >> 6, lane = tid & 63;
  const int wm = wave >> 1, wn = wave & 1;
  const int l15 = lane & 15, lhi = lane >> 4;
  f32x4 acc[4][4] = {};

  for (int k0 = 0; k0 < 512; k0 += 32) {
    #pragma unroll
    for (int it = 0; it < 2; ++it) {
      const int ss  = tid + it * 256;
      const int row = ss >> 2;
      const int c8  = (ss & 3) << 3;
      *(uint4*)(As + row * 32 + c8) =
          *(const uint4*)(A + (size_t)(tm * 128 + row) * 512 + k0 + c8);
      const float4 b0 = *(const float4*)(Bw + (size_t)(tn * 128 + row) * 512 + k0 + c8);
      const float4 b1 = *(const float4*)(Bw + (size_t)(tn * 128 + row) * 512 + k0 + c8 + 4);
      union { unsigned short h[8]; uint4 u; } cv;
      cv.h[0] = f2bf(b0.x); cv.h[1] = f2bf(b0.y); cv.h[2] = f2bf(b0.z); cv.h[3] = f2bf(b0.w);
      cv.h[4] = f2bf(b1.x); cv.h[5] = f2bf(b1.y); cv.h[6] = f2bf(b1.z); cv.h[7] = f2bf(b1.w);
      *(uint4*)(Bs + row * 32 + c8) = cv.u;
    }
    __syncthreads();
    sh8 af[4], bfr[4];
    #pragma unroll
    for (int mi = 0; mi < 4; ++mi)
      af[mi] = *(const sh8*)(As + (wm * 64 + mi * 16 + l15) * 32 + lhi * 8);
    #pragma unroll
    for (int ni = 0; ni < 4; ++ni)
      bfr[ni] = *(const sh8*)(Bs + (wn * 64 + ni * 16 + l15) * 32 + lhi * 8);
    #pragma unroll
    for (int mi = 0; mi < 4; ++mi)
      #pragma unroll
      for (int ni = 0; ni < 4; ++ni)
        acc[mi][ni] = __builtin_amdgcn_mfma_f32_16x16x32_bf16(af[mi], bfr[ni], acc[mi][ni], 0, 0, 0);
    __syncthreads();
  }

  #pragma unroll
  for (int ni = 0; ni < 4; ++ni) {
    const int col = tn * 128 + wn * 64 + ni * 16 + l15;
    const float bv = bias[col];
    #pragma unroll
    for (int mi = 0; mi < 4; ++mi) {
      const int row0 = tm * 128 + wm * 64 + mi * 16 + lhi * 4;
      #pragma unroll
      for (int q = 0; q < 4; ++q)
        Y[(size_t)(row0 + q) * VSZ + col] = acc[mi][ni][q] + bv;
    }
  }
}

extern "C" void kernel_launch(void* const* d_in, const int* in_sizes, int n_in,
                              void* d_out, int out_size, void* d_ws, size_t ws_size,
                              hipStream_t stream)
{
  const int*   x   = (const int*)  d_in[0];
  const float* emb = (const float*)d_in[1];
  const float* Wr  = (const float*)d_in[2];
  const float* Br  = (const float*)d_in[3];
  const float* Wz  = (const float*)d_in[4];
  const float* Bz  = (const float*)d_in[5];
  const float* Wh  = (const float*)d_in[6];
  const float* Bh  = (const float*)d_in[7];
  const float* W   = (const float*)d_in[8];
  const float* bo  = (const float*)d_in[9];
  float* out = (float*)d_out;

  char* ws = (char*)d_ws;
  float*          h32   = (float*)(ws);                    // 128 KiB [64][512]
  float*          z32   = (float*)(ws + 131072);           // 128 KiB [64][512]
  _Float16*       hF    = (_Float16*)(ws + 262144);        //  64 KiB [64][512]
  _Float16*       uF    = (_Float16*)(ws + 327680);        //  64 KiB [64][512]
  unsigned*       flags = (unsigned*)(ws + 393216);        //   4 KiB flags (128B/WG)
  unsigned short* Habf  = (unsigned short*)(ws + 397312);  //   8 MiB bf16 h history

  // XG (pre-projection) overlays d_out; dead before out_gemm writes Y.
  float* XG   = out;                  // [8192][1536]
  float* outT = out + 262144000ll;    // hT.T region

  // zero h32, z32, hF, uF, barrier flags (deterministic across graph replays)
  (void)hipMemsetAsync(ws, 0, 397312, stream);

  proj_kernel<<<dim3(24, 128), 256, 0, stream>>>(x, emb, Wr, Br, Wz, Bz, Wh, Bh, XG);
  recur_kernel<<<NWG, 256, 0, stream>>>(XG, Wr, Wz, Wh, h32, z32, hF, uF, Habf, outT, flags);
  out_gemm_kernel<<<16000, 256, 0, stream>>>(Habf, W, bo, out);
}

// Round 10
// 2033.356 us; speedup vs baseline: 3.1036x; 1.1816x over previous
//
#include <hip/hip_runtime.h>
#include <cstdint>
#include <cstddef>

#define VSZ 32000
#define ED  512
#define HD  512
#define SQ  128
#define BA  64
#define INW 1024
#define NG  1536
#define NWG 32
#define FLG 32   // flag stride in dwords (one 128B line per WG)

typedef __attribute__((ext_vector_type(8))) short sh8;
typedef __attribute__((ext_vector_type(4))) float f32x4;
typedef _Float16 half8 __attribute__((ext_vector_type(8)));
typedef unsigned u32x4 __attribute__((ext_vector_type(4)));

__device__ inline unsigned short f2bf(float f) {
  unsigned int u = __float_as_uint(f);
  u += 0x7fffu + ((u >> 16) & 1u);
  return (unsigned short)(u >> 16);
}

// Device-scope 16B load (bypass L1+L2, read L3 coherence point). Burst-issue,
// then ONE s_waitcnt vmcnt(0) + sched_barrier(0) before consuming.
__device__ __forceinline__ half8 ld_h8_dev(const _Float16* p) {
  u32x4 r;
  asm volatile("global_load_dwordx4 %0, %1, off sc0 sc1" : "=v"(r) : "v"(p));
  return __builtin_bit_cast(half8, r);
}

__device__ __forceinline__ void st_u32_dev(unsigned* p, unsigned v) {
  asm volatile("global_store_dword %0, %1, off sc0 sc1" :: "v"(p), "v"(v) : "memory");
}

__device__ __forceinline__ void st_u32_plain(unsigned* p, unsigned v) {
  asm volatile("global_store_dword %0, %1, off" :: "v"(p), "v"(v) : "memory");
}

__device__ __forceinline__ unsigned ld_u32_dev(const unsigned* p) {
  unsigned r;
  asm volatile("global_load_dword %0, %1, off sc0 sc1" : "=v"(r) : "v"(p));
  asm volatile("s_waitcnt vmcnt(0)" ::: "memory");
  __builtin_amdgcn_sched_barrier(0);
  return r;
}

// Grid barrier: per-WG flag (one L3 line each); every wave polls independently
// and proceeds on its own observation (no trailing __syncthreads).
__device__ __forceinline__ void gridbar(unsigned* flags, unsigned epoch, int wg) {
  asm volatile("s_waitcnt vmcnt(0)" ::: "memory");   // drain this wave's data stores
  __syncthreads();                                   // all waves drained
  if (threadIdx.x == 0) st_u32_dev(flags + wg * FLG, epoch);
  const unsigned* fp = flags + (threadIdx.x & (NWG - 1)) * FLG;
  unsigned v = ld_u32_dev(fp);
  while (!__all((int)(v >= epoch))) v = ld_u32_dev(fp);
}

// ---------------- pre-projection (fp16 MFMA): XG = emb[x] @ {Wr,Wz,Wh}[:,:512]^T + bias ------
// Tile 128x128, 4 waves (2x2), K=512. A rows gathered via x[m]; operands f32->f16 on stage.
__global__ __launch_bounds__(256) void proj_kernel(
    const int* __restrict__ x, const float* __restrict__ emb,
    const float* __restrict__ Wr, const float* __restrict__ Br,
    const float* __restrict__ Wz, const float* __restrict__ Bz,
    const float* __restrict__ Wh, const float* __restrict__ Bh,
    float* __restrict__ XG)
{
  __shared__ _Float16 As[128 * 40];
  __shared__ _Float16 Bs[128 * 40];
  const int tn = blockIdx.x;           // 0..11 (N tile; gate = tn>>2, no straddle)
  const int tm = blockIdx.y;           // 0..63 (M tile)
  const int g  = tn >> 2;
  const float* Wsrc = (g == 0 ? Wr : (g == 1 ? Wz : Wh));
  const float* Bias = (g == 0 ? Br : (g == 1 ? Bz : Bh));
  const int jj0 = (tn & 3) * 128;      // row base within the gate's weight matrix
  const int tid = threadIdx.x;
  const int wave = tid >> 6, lane = tid & 63;
  const int wm = wave >> 1, wn = wave & 1;
  const int l15 = lane & 15, lhi = lane >> 4;
  f32x4 acc[4][4] = {};

  for (int k0 = 0; k0 < ED; k0 += 32) {
    #pragma unroll
    for (int it = 0; it < 2; ++it) {
      const int c = tid + it * 256;            // 0..511 chunks (128 rows x 4)
      const int row = c >> 2, c8 = (c & 3) << 3;
      {
        const int src = x[tm * 128 + row];
        const float4 a0 = *(const float4*)(emb + (size_t)src * ED + k0 + c8);
        const float4 a1 = *(const float4*)(emb + (size_t)src * ED + k0 + c8 + 4);
        half8 w;
        w[0]=(_Float16)a0.x; w[1]=(_Float16)a0.y; w[2]=(_Float16)a0.z; w[3]=(_Float16)a0.w;
        w[4]=(_Float16)a1.x; w[5]=(_Float16)a1.y; w[6]=(_Float16)a1.z; w[7]=(_Float16)a1.w;
        *(half8*)(As + row * 40 + c8) = w;
      }
      {
        const float* wr = Wsrc + (size_t)(jj0 + row) * INW + k0 + c8;
        const float4 b0 = *(const float4*)(wr);
        const float4 b1 = *(const float4*)(wr + 4);
        half8 w;
        w[0]=(_Float16)b0.x; w[1]=(_Float16)b0.y; w[2]=(_Float16)b0.z; w[3]=(_Float16)b0.w;
        w[4]=(_Float16)b1.x; w[5]=(_Float16)b1.y; w[6]=(_Float16)b1.z; w[7]=(_Float16)b1.w;
        *(half8*)(Bs + row * 40 + c8) = w;
      }
    }
    __syncthreads();
    half8 af[4], bf[4];
    #pragma unroll
    for (int mi = 0; mi < 4; ++mi)
      af[mi] = *(const half8*)(As + (wm * 64 + mi * 16 + l15) * 40 + lhi * 8);
    #pragma unroll
    for (int ni = 0; ni < 4; ++ni)
      bf[ni] = *(const half8*)(Bs + (wn * 64 + ni * 16 + l15) * 40 + lhi * 8);
    #pragma unroll
    for (int mi = 0; mi < 4; ++mi)
      #pragma unroll
      for (int ni = 0; ni < 4; ++ni)
        acc[mi][ni] = __builtin_amdgcn_mfma_f32_16x16x32_f16(af[mi], bf[ni], acc[mi][ni], 0, 0, 0);
    __syncthreads();
  }
  #pragma unroll
  for (int ni = 0; ni < 4; ++ni) {
    const int jc = tn * 128 + wn * 64 + ni * 16 + l15;
    const float bv = Bias[jj0 + wn * 64 + ni * 16 + l15];
    #pragma unroll
    for (int mi = 0; mi < 4; ++mi) {
      const int m0 = tm * 128 + wm * 64 + mi * 16 + lhi * 4;
      #pragma unroll
      for (int q = 0; q < 4; ++q)
        XG[(size_t)(m0 + q) * NG + jc] = acc[mi][ni][q] + bv;
    }
  }
}

// ---------------- persistent GRU recurrence (h,z in registers; all-asm loop memory) ----------
// 32 WGs x 256 thr (4 waves). WG w owns columns w*16..+15 of r, z AND h_cand.
__global__ __launch_bounds__(256) void recur_kernel(
    const float* __restrict__ XG,     // [8192][1536]
    const float* __restrict__ Wr, const float* __restrict__ Wz, const float* __restrict__ Wh,
    _Float16* __restrict__ hF,        // [64][512] fp16 (device-coherent)
    _Float16* __restrict__ uF,        // [64][512] fp16 (device-coherent, r*h)
    unsigned short* __restrict__ Habf,// [8192][512] bf16
    float* __restrict__ outT,         // [512][64]  (hT.T)
    unsigned* __restrict__ flags)
{
  const int tid = threadIdx.x, wg = blockIdx.x;
  const int wv = tid >> 6, lane = tid & 63;
  const int l15 = lane & 15, lhi = lane >> 4;
  const int mrow = wv * 16 + l15;          // A-fragment row (batch)
  const int col  = wg * 16 + l15;          // owned column (same for r, z, h_cand)

  // ---- weight B-fragments in registers (fp16), loaded once ----
  half8 wfR[16], wfZ[16], wfH[16];
  {
    const float* WR = Wr + (size_t)col * INW + ED + lhi * 8;
    const float* WZ = Wz + (size_t)col * INW + ED + lhi * 8;
    const float* WH = Wh + (size_t)col * INW + ED + lhi * 8;
    #pragma unroll
    for (int s = 0; s < 16; ++s) {
      float4 a, b; half8 w;
      a = *(const float4*)(WR + s * 32); b = *(const float4*)(WR + s * 32 + 4);
      w[0]=(_Float16)a.x; w[1]=(_Float16)a.y; w[2]=(_Float16)a.z; w[3]=(_Float16)a.w;
      w[4]=(_Float16)b.x; w[5]=(_Float16)b.y; w[6]=(_Float16)b.z; w[7]=(_Float16)b.w;
      wfR[s] = w;
      a = *(const float4*)(WZ + s * 32); b = *(const float4*)(WZ + s * 32 + 4);
      w[0]=(_Float16)a.x; w[1]=(_Float16)a.y; w[2]=(_Float16)a.z; w[3]=(_Float16)a.w;
      w[4]=(_Float16)b.x; w[5]=(_Float16)b.y; w[6]=(_Float16)b.z; w[7]=(_Float16)b.w;
      wfZ[s] = w;
      a = *(const float4*)(WH + s * 32); b = *(const float4*)(WH + s * 32 + 4);
      w[0]=(_Float16)a.x; w[1]=(_Float16)a.y; w[2]=(_Float16)a.z; w[3]=(_Float16)a.w;
      w[4]=(_Float16)b.x; w[5]=(_Float16)b.y; w[6]=(_Float16)b.z; w[7]=(_Float16)b.w;
      wfH[s] = w;
    }
  }

  // per-thread GRU state (same (b,col) handled by this thread in both phases)
  float hreg[4] = {0.f, 0.f, 0.f, 0.f};
  float zreg[4];
  // XG for step 0
  float xgR[4], xgZ[4], xgH[4];
  #pragma unroll
  for (int q = 0; q < 4; ++q) {
    const int b = wv * 16 + lhi * 4 + q;
    const float* xp = XG + (size_t)b * NG + col;
    xgR[q] = xp[0]; xgZ[q] = xp[512]; xgH[q] = xp[1024];
  }

  unsigned epoch = 0;
  for (int t = 0; t < SQ; ++t) {
    float nR[4] = {0,0,0,0}, nZ[4] = {0,0,0,0}, nH[4] = {0,0,0,0};
    // ---- phase A: preR/preZ = h @ W{r,z}h^T ; sigmoid -> uF (dev), z in regs ----
    {
      half8 ha[16];
      #pragma unroll
      for (int s = 0; s < 16; ++s)
        ha[s] = ld_h8_dev(hF + (size_t)mrow * HD + s * 32 + lhi * 8);
      asm volatile("s_waitcnt vmcnt(0)" ::: "memory");
      __builtin_amdgcn_sched_barrier(0);

      // next-step XG prefetch (plain cached; overlaps MFMA + epilogue)
      if (t + 1 < SQ) {
        #pragma unroll
        for (int q = 0; q < 4; ++q) {
          const int b = wv * 16 + lhi * 4 + q;
          const float* xp = XG + (size_t)(t + 1) * BA * NG + (size_t)b * NG + col;
          nR[q] = xp[0]; nZ[q] = xp[512]; nH[q] = xp[1024];
        }
      }

      f32x4 accR = {}, accZ = {};
      #pragma unroll
      for (int s = 0; s < 16; ++s) {
        accR = __builtin_amdgcn_mfma_f32_16x16x32_f16(ha[s], wfR[s], accR, 0, 0, 0);
        accZ = __builtin_amdgcn_mfma_f32_16x16x32_f16(ha[s], wfZ[s], accZ, 0, 0, 0);
      }
      #pragma unroll
      for (int q = 0; q < 4; ++q) {
        const int b = wv * 16 + lhi * 4 + q;
        const float preR = accR[q] + xgR[q];
        const float r  = 1.0f / (1.0f + __expf(-preR));
        const _Float16 uh = (_Float16)(r * hreg[q]);
        const unsigned short ub = __builtin_bit_cast(unsigned short, uh);
        const unsigned short ob = (unsigned short)__shfl_xor((int)ub, 1);
        if (!(l15 & 1))
          st_u32_dev((unsigned*)(uF + (size_t)b * HD + col),
                     (unsigned)ub | ((unsigned)ob << 16));
        zreg[q] = 1.0f / (1.0f + __expf(-(accZ[q] + xgZ[q])));
      }
    }
    ++epoch; gridbar(flags, epoch, wg);

    // ---- phase B: pre = u @ Whh^T ; tanh + combine -> hreg, hF (dev), Habf ----
    {
      half8 ua[16];
      #pragma unroll
      for (int s = 0; s < 16; ++s)
        ua[s] = ld_h8_dev(uF + (size_t)mrow * HD + s * 32 + lhi * 8);
      asm volatile("s_waitcnt vmcnt(0)" ::: "memory");
      __builtin_amdgcn_sched_barrier(0);
      f32x4 acc = {};
      #pragma unroll
      for (int s = 0; s < 16; ++s)
        acc = __builtin_amdgcn_mfma_f32_16x16x32_f16(ua[s], wfH[s], acc, 0, 0, 0);

      #pragma unroll
      for (int q = 0; q < 4; ++q) {
        const int b = wv * 16 + lhi * 4 + q;
        const float pre = acc[q] + xgH[q];
        const float e  = __expf(2.0f * pre);          // tanh, inf-safe
        const float hc = 1.0f - 2.0f / (e + 1.0f);
        const float hn = zreg[q] * hreg[q] + (1.0f - zreg[q]) * hc;
        hreg[q] = hn;
        const _Float16 hh = (_Float16)hn;
        const unsigned short hb = __builtin_bit_cast(unsigned short, hh);
        const unsigned short hob = (unsigned short)__shfl_xor((int)hb, 1);
        const unsigned short bb = f2bf(hn);
        const unsigned short bob = (unsigned short)__shfl_xor((int)bb, 1);
        if (!(l15 & 1)) {
          st_u32_dev((unsigned*)(hF + (size_t)b * HD + col),
                     (unsigned)hb | ((unsigned)hob << 16));
          st_u32_plain((unsigned*)(Habf + (size_t)(t * BA + b) * HD + col),
                       (unsigned)bb | ((unsigned)bob << 16));
        }
        if (t == SQ - 1) outT[col * BA + b] = hn;
        xgR[q] = nR[q]; xgZ[q] = nZ[q]; xgH[q] = nH[q];
      }
    }
    ++epoch; gridbar(flags, epoch, wg);
  }
}

// ---------------- final output GEMM: Y = Habf @ W^T + b (256x256 tile, 8 waves, swizzled) -----
__global__ __launch_bounds__(512) void out_gemm_kernel(
    const unsigned short* __restrict__ A,  // 8192 x 512 bf16
    const float* __restrict__ Bw,          // 32000 x 512 f32
    const float* __restrict__ bias,        // 32000
    float* __restrict__ Y)                 // 8192 x 32000
{
  __shared__ unsigned short As[256 * 40];
  __shared__ unsigned short Bs[256 * 40];
  const int bid = blockIdx.x;
  const int s  = (bid & 7) * 500 + (bid >> 3);   // bijective XCD swizzle (4000 = 8*500)
  const int tm = s / 125, tn = s % 125;
  const int tid = threadIdx.x;
  const int wave = tid >> 6, lane = tid & 63;
  const int wm = wave >> 2, wn = wave & 3;
  const int l15 = lane & 15, lhi = lane >> 4;
  f32x4 acc[8][4] = {};

  for (int k0 = 0; k0 < 512; k0 += 32) {
    #pragma unroll
    for (int it = 0; it < 2; ++it) {
      const int c = tid + it * 512;              // 0..1023 chunks (256 rows x 4)
      const int row = c >> 2, c8 = (c & 3) << 3;
      *(uint4*)(As + row * 40 + c8) =
          *(const uint4*)(A + (size_t)(tm * 256 + row) * 512 + k0 + c8);
      const float4 b0 = *(const float4*)(Bw + (size_t)(tn * 256 + row) * 512 + k0 + c8);
      const float4 b1 = *(const float4*)(Bw + (size_t)(tn * 256 + row) * 512 + k0 + c8 + 4);
      union { unsigned short h[8]; uint4 u; } cv;
      cv.h[0] = f2bf(b0.x); cv.h[1] = f2bf(b0.y); cv.h[2] = f2bf(b0.z); cv.h[3] = f2bf(b0.w);
      cv.h[4] = f2bf(b1.x); cv.h[5] = f2bf(b1.y); cv.h[6] = f2bf(b1.z); cv.h[7] = f2bf(b1.w);
      *(uint4*)(Bs + row * 40 + c8) = cv.u;
    }
    __syncthreads();
    sh8 af[8], bf[4];
    #pragma unroll
    for (int mi = 0; mi < 8; ++mi)
      af[mi] = *(const sh8*)(As + (wm * 128 + mi * 16 + l15) * 40 + lhi * 8);
    #pragma unroll
    for (int ni = 0; ni < 4; ++ni)
      bf[ni] = *(const sh8*)(Bs + (wn * 64 + ni * 16 + l15) * 40 + lhi * 8);
    #pragma unroll
    for (int mi = 0; mi < 8; ++mi)
      #pragma unroll
      for (int ni = 0; ni < 4; ++ni)
        acc[mi][ni] = __builtin_amdgcn_mfma_f32_16x16x32_bf16(af[mi], bf[ni], acc[mi][ni], 0, 0, 0);
    __syncthreads();
  }

  #pragma unroll
  for (int ni = 0; ni < 4; ++ni) {
    const int colc = tn * 256 + wn * 64 + ni * 16 + l15;
    const float bv = bias[colc];
    #pragma unroll
    for (int mi = 0; mi < 8; ++mi) {
      const int row0 = tm * 256 + wm * 128 + mi * 16 + lhi * 4;
      #pragma unroll
      for (int q = 0; q < 4; ++q)
        Y[(size_t)(row0 + q) * VSZ + colc] = acc[mi][ni][q] + bv;
    }
  }
}

extern "C" void kernel_launch(void* const* d_in, const int* in_sizes, int n_in,
                              void* d_out, int out_size, void* d_ws, size_t ws_size,
                              hipStream_t stream)
{
  const int*   x   = (const int*)  d_in[0];
  const float* emb = (const float*)d_in[1];
  const float* Wr  = (const float*)d_in[2];
  const float* Br  = (const float*)d_in[3];
  const float* Wz  = (const float*)d_in[4];
  const float* Bz  = (const float*)d_in[5];
  const float* Wh  = (const float*)d_in[6];
  const float* Bh  = (const float*)d_in[7];
  const float* W   = (const float*)d_in[8];
  const float* bo  = (const float*)d_in[9];
  float* out = (float*)d_out;

  char* ws = (char*)d_ws;
  _Float16*       hF    = (_Float16*)(ws);                 //  64 KiB [64][512]
  _Float16*       uF    = (_Float16*)(ws + 65536);         //  64 KiB [64][512]
  unsigned*       flags = (unsigned*)(ws + 131072);        //   4 KiB flags (128B/WG)
  unsigned short* Habf  = (unsigned short*)(ws + 135168);  //   8 MiB bf16 h history

  // XG (pre-projection) overlays d_out; dead before out_gemm writes Y.
  float* XG   = out;                  // [8192][1536]
  float* outT = out + 262144000ll;    // hT.T region

  // zero hF, uF, flags (deterministic across graph replays)
  (void)hipMemsetAsync(ws, 0, 135168, stream);

  proj_kernel<<<dim3(12, 64), 256, 0, stream>>>(x, emb, Wr, Br, Wz, Bz, Wh, Bh, XG);
  recur_kernel<<<NWG, 256, 0, stream>>>(XG, Wr, Wz, Wh, hF, uF, Habf, outT, flags);
  out_gemm_kernel<<<4000, 512, 0, stream>>>(Habf, W, bo, out);
}

// Round 11
// 1867.431 us; speedup vs baseline: 3.3794x; 1.0889x over previous
//
#include <hip/hip_runtime.h>
#include <cstdint>
#include <cstddef>

#define VSZ 32000
#define ED  512
#define HD  512
#define SQ  128
#define BA  64
#define INW 1024
#define NG  1536
#define NWG 32
#define FLG 32   // flag stride in dwords (one 128B line per wave-slot)

typedef __attribute__((ext_vector_type(8))) short sh8;
typedef __attribute__((ext_vector_type(4))) float f32x4;
typedef _Float16 half8 __attribute__((ext_vector_type(8)));
typedef unsigned u32x4 __attribute__((ext_vector_type(4)));

__device__ inline unsigned short f2bf(float f) {
  unsigned int u = __float_as_uint(f);
  u += 0x7fffu + ((u >> 16) & 1u);
  return (unsigned short)(u >> 16);
}

// Device-scope 16B load (bypass L1+L2, read at L3 coherence point). Burst-issue,
// then ONE s_waitcnt vmcnt(0) + sched_barrier(0) before consuming.
__device__ __forceinline__ half8 ld_h8_dev(const _Float16* p) {
  u32x4 r;
  asm volatile("global_load_dwordx4 %0, %1, off sc0 sc1" : "=v"(r) : "v"(p));
  return __builtin_bit_cast(half8, r);
}

__device__ __forceinline__ void st_u32_dev(unsigned* p, unsigned v) {
  asm volatile("global_store_dword %0, %1, off sc0 sc1" :: "v"(p), "v"(v) : "memory");
}

__device__ __forceinline__ void st_u32_plain(unsigned* p, unsigned v) {
  asm volatile("global_store_dword %0, %1, off" :: "v"(p), "v"(v) : "memory");
}

__device__ __forceinline__ unsigned ld_u32_dev(const unsigned* p) {
  unsigned r;
  asm volatile("global_load_dword %0, %1, off sc0 sc1" : "=v"(r) : "v"(p));
  asm volatile("s_waitcnt vmcnt(0)" ::: "memory");
  __builtin_amdgcn_sched_barrier(0);
  return r;
}

// Wave-autonomous signal: drain this wave's device-scope data stores, then
// publish epoch. sched_barrier keeps later compute from hoisting above.
__device__ __forceinline__ void wave_signal(unsigned* flags, unsigned epoch, int slot, int lane) {
  asm volatile("s_waitcnt vmcnt(0)" ::: "memory");
  if (lane == 0) st_u32_dev(flags + slot * FLG, epoch);
  __builtin_amdgcn_sched_barrier(0);
}

// Wave-autonomous wait: lane l polls producer-WG (l&31)'s wave-wv flag.
__device__ __forceinline__ void wave_wait(const unsigned* flags, unsigned epoch, int wv, int lane) {
  const unsigned* fp = flags + (((lane & 31) << 2) + wv) * FLG;
  unsigned v = ld_u32_dev(fp);
  while (!__all((int)(v >= epoch))) v = ld_u32_dev(fp);
}

// ---------------- pre-projection (fp16 MFMA): XG = emb[x] @ {Wr,Wz,Wh}[:,:512]^T + bias ------
__global__ __launch_bounds__(256) void proj_kernel(
    const int* __restrict__ x, const float* __restrict__ emb,
    const float* __restrict__ Wr, const float* __restrict__ Br,
    const float* __restrict__ Wz, const float* __restrict__ Bz,
    const float* __restrict__ Wh, const float* __restrict__ Bh,
    float* __restrict__ XG)
{
  __shared__ _Float16 As[128 * 40];
  __shared__ _Float16 Bs[128 * 40];
  const int tn = blockIdx.x;           // 0..11 (N tile; gate = tn>>2, no straddle)
  const int tm = blockIdx.y;           // 0..63 (M tile)
  const int g  = tn >> 2;
  const float* Wsrc = (g == 0 ? Wr : (g == 1 ? Wz : Wh));
  const float* Bias = (g == 0 ? Br : (g == 1 ? Bz : Bh));
  const int jj0 = (tn & 3) * 128;      // row base within the gate's weight matrix
  const int tid = threadIdx.x;
  const int wave = tid >> 6, lane = tid & 63;
  const int wm = wave >> 1, wn = wave & 1;
  const int l15 = lane & 15, lhi = lane >> 4;
  f32x4 acc[4][4] = {};

  for (int k0 = 0; k0 < ED; k0 += 32) {
    #pragma unroll
    for (int it = 0; it < 2; ++it) {
      const int c = tid + it * 256;            // 0..511 chunks (128 rows x 4)
      const int row = c >> 2, c8 = (c & 3) << 3;
      {
        const int src = x[tm * 128 + row];
        const float4 a0 = *(const float4*)(emb + (size_t)src * ED + k0 + c8);
        const float4 a1 = *(const float4*)(emb + (size_t)src * ED + k0 + c8 + 4);
        half8 w;
        w[0]=(_Float16)a0.x; w[1]=(_Float16)a0.y; w[2]=(_Float16)a0.z; w[3]=(_Float16)a0.w;
        w[4]=(_Float16)a1.x; w[5]=(_Float16)a1.y; w[6]=(_Float16)a1.z; w[7]=(_Float16)a1.w;
        *(half8*)(As + row * 40 + c8) = w;
      }
      {
        const float* wr = Wsrc + (size_t)(jj0 + row) * INW + k0 + c8;
        const float4 b0 = *(const float4*)(wr);
        const float4 b1 = *(const float4*)(wr + 4);
        half8 w;
        w[0]=(_Float16)b0.x; w[1]=(_Float16)b0.y; w[2]=(_Float16)b0.z; w[3]=(_Float16)b0.w;
        w[4]=(_Float16)b1.x; w[5]=(_Float16)b1.y; w[6]=(_Float16)b1.z; w[7]=(_Float16)b1.w;
        *(half8*)(Bs + row * 40 + c8) = w;
      }
    }
    __syncthreads();
    half8 af[4], bf[4];
    #pragma unroll
    for (int mi = 0; mi < 4; ++mi)
      af[mi] = *(const half8*)(As + (wm * 64 + mi * 16 + l15) * 40 + lhi * 8);
    #pragma unroll
    for (int ni = 0; ni < 4; ++ni)
      bf[ni] = *(const half8*)(Bs + (wn * 64 + ni * 16 + l15) * 40 + lhi * 8);
    #pragma unroll
    for (int mi = 0; mi < 4; ++mi)
      #pragma unroll
      for (int ni = 0; ni < 4; ++ni)
        acc[mi][ni] = __builtin_amdgcn_mfma_f32_16x16x32_f16(af[mi], bf[ni], acc[mi][ni], 0, 0, 0);
    __syncthreads();
  }
  #pragma unroll
  for (int ni = 0; ni < 4; ++ni) {
    const int jc = tn * 128 + wn * 64 + ni * 16 + l15;
    const float bv = Bias[jj0 + wn * 64 + ni * 16 + l15];
    #pragma unroll
    for (int mi = 0; mi < 4; ++mi) {
      const int m0 = tm * 128 + wm * 64 + mi * 16 + lhi * 4;
      #pragma unroll
      for (int q = 0; q < 4; ++q)
        XG[(size_t)(m0 + q) * NG + jc] = acc[mi][ni][q] + bv;
    }
  }
}

// ---------------- persistent GRU recurrence (wave-autonomous flags, no __syncthreads) --------
// 32 WGs x 256 thr (4 waves). WG w owns columns w*16..+15 of r, z AND h_cand.
// Wave wv exchanges only rows wv*16..+15 -> per-wave flag slots [wg*4+wv].
__global__ __launch_bounds__(256) void recur_kernel(
    const float* __restrict__ XG,     // [8192][1536]
    const float* __restrict__ Wr, const float* __restrict__ Wz, const float* __restrict__ Wh,
    _Float16* __restrict__ hF,        // [64][512] fp16 (device-coherent)
    _Float16* __restrict__ uF,        // [64][512] fp16 (device-coherent, r*h)
    unsigned short* __restrict__ Habf,// [8192][512] bf16
    float* __restrict__ outT,         // [512][64]  (hT.T)
    unsigned* __restrict__ flagsA,
    unsigned* __restrict__ flagsB)
{
  const int tid = threadIdx.x, wg = blockIdx.x;
  const int wv = tid >> 6, lane = tid & 63;
  const int l15 = lane & 15, lhi = lane >> 4;
  const int mrow = wv * 16 + l15;          // A-fragment row (batch)
  const int col  = wg * 16 + l15;          // owned column (same for r, z, h_cand)
  const int slot = wg * 4 + wv;

  // ---- weight B-fragments in registers (fp16), loaded once ----
  half8 wfR[16], wfZ[16], wfH[16];
  {
    const float* WR = Wr + (size_t)col * INW + ED + lhi * 8;
    const float* WZ = Wz + (size_t)col * INW + ED + lhi * 8;
    const float* WH = Wh + (size_t)col * INW + ED + lhi * 8;
    #pragma unroll
    for (int s = 0; s < 16; ++s) {
      float4 a, b; half8 w;
      a = *(const float4*)(WR + s * 32); b = *(const float4*)(WR + s * 32 + 4);
      w[0]=(_Float16)a.x; w[1]=(_Float16)a.y; w[2]=(_Float16)a.z; w[3]=(_Float16)a.w;
      w[4]=(_Float16)b.x; w[5]=(_Float16)b.y; w[6]=(_Float16)b.z; w[7]=(_Float16)b.w;
      wfR[s] = w;
      a = *(const float4*)(WZ + s * 32); b = *(const float4*)(WZ + s * 32 + 4);
      w[0]=(_Float16)a.x; w[1]=(_Float16)a.y; w[2]=(_Float16)a.z; w[3]=(_Float16)a.w;
      w[4]=(_Float16)b.x; w[5]=(_Float16)b.y; w[6]=(_Float16)b.z; w[7]=(_Float16)b.w;
      wfZ[s] = w;
      a = *(const float4*)(WH + s * 32); b = *(const float4*)(WH + s * 32 + 4);
      w[0]=(_Float16)a.x; w[1]=(_Float16)a.y; w[2]=(_Float16)a.z; w[3]=(_Float16)a.w;
      w[4]=(_Float16)b.x; w[5]=(_Float16)b.y; w[6]=(_Float16)b.z; w[7]=(_Float16)b.w;
      wfH[s] = w;
    }
  }

  // per-thread GRU state (same (b,col) handled by this thread in both phases)
  float hreg[4] = {0.f, 0.f, 0.f, 0.f};
  float zreg[4];
  // XG for step 0
  float xgR[4], xgZ[4], xgH[4];
  #pragma unroll
  for (int q = 0; q < 4; ++q) {
    const int b = wv * 16 + lhi * 4 + q;
    const float* xp = XG + (size_t)b * NG + col;
    xgR[q] = xp[0]; xgZ[q] = xp[512]; xgH[q] = xp[1024];
  }

  for (int t = 0; t < SQ; ++t) {
    const unsigned ep = (unsigned)(t + 1);
    // ---- wait for h of step t (phase B of t-1); t=0 passes trivially ----
    wave_wait(flagsB, (unsigned)t, wv, lane);

    // ---- phase A critical path: load h, R-GEMM, u = sigmoid(preR)*h, store+signal ----
    half8 ha[16];
    #pragma unroll
    for (int s = 0; s < 16; ++s)
      ha[s] = ld_h8_dev(hF + (size_t)mrow * HD + s * 32 + lhi * 8);
    asm volatile("s_waitcnt vmcnt(0)" ::: "memory");
    __builtin_amdgcn_sched_barrier(0);

    f32x4 accR = {};
    #pragma unroll
    for (int s = 0; s < 16; ++s)
      accR = __builtin_amdgcn_mfma_f32_16x16x32_f16(ha[s], wfR[s], accR, 0, 0, 0);
    #pragma unroll
    for (int q = 0; q < 4; ++q) {
      const int b = wv * 16 + lhi * 4 + q;
      const float r = 1.0f / (1.0f + __expf(-(accR[q] + xgR[q])));
      const _Float16 uh = (_Float16)(r * hreg[q]);
      const unsigned short ub = __builtin_bit_cast(unsigned short, uh);
      const unsigned short ob = (unsigned short)__shfl_xor((int)ub, 1);
      if (!(l15 & 1))
        st_u32_dev((unsigned*)(uF + (size_t)b * HD + col),
                   (unsigned)ub | ((unsigned)ob << 16));
    }
    wave_signal(flagsA, ep, slot, lane);

    // ---- off-path: Z-GEMM + z sigmoid + next-step XG prefetch (hides propagation) ----
    f32x4 accZ = {};
    #pragma unroll
    for (int s = 0; s < 16; ++s)
      accZ = __builtin_amdgcn_mfma_f32_16x16x32_f16(ha[s], wfZ[s], accZ, 0, 0, 0);
    float nR[4] = {0,0,0,0}, nZ[4] = {0,0,0,0}, nH[4] = {0,0,0,0};
    if (t + 1 < SQ) {
      #pragma unroll
      for (int q = 0; q < 4; ++q) {
        const int b = wv * 16 + lhi * 4 + q;
        const float* xp = XG + (size_t)(t + 1) * BA * NG + (size_t)b * NG + col;
        nR[q] = xp[0]; nZ[q] = xp[512]; nH[q] = xp[1024];
      }
    }
    #pragma unroll
    for (int q = 0; q < 4; ++q)
      zreg[q] = 1.0f / (1.0f + __expf(-(accZ[q] + xgZ[q])));

    // ---- phase B: wait u, H-GEMM, combine, store h + signal ----
    wave_wait(flagsA, ep, wv, lane);
    half8 ua[16];
    #pragma unroll
    for (int s = 0; s < 16; ++s)
      ua[s] = ld_h8_dev(uF + (size_t)mrow * HD + s * 32 + lhi * 8);
    asm volatile("s_waitcnt vmcnt(0)" ::: "memory");
    __builtin_amdgcn_sched_barrier(0);
    f32x4 acc = {};
    #pragma unroll
    for (int s = 0; s < 16; ++s)
      acc = __builtin_amdgcn_mfma_f32_16x16x32_f16(ua[s], wfH[s], acc, 0, 0, 0);

    unsigned habw[4]; int habst[4];
    #pragma unroll
    for (int q = 0; q < 4; ++q) {
      const int b = wv * 16 + lhi * 4 + q;
      const float e  = __expf(2.0f * (acc[q] + xgH[q]));   // tanh, inf-safe
      const float hc = 1.0f - 2.0f / (e + 1.0f);
      const float hn = zreg[q] * hreg[q] + (1.0f - zreg[q]) * hc;
      hreg[q] = hn;
      const _Float16 hh = (_Float16)hn;
      const unsigned short hb = __builtin_bit_cast(unsigned short, hh);
      const unsigned short hob = (unsigned short)__shfl_xor((int)hb, 1);
      if (!(l15 & 1))
        st_u32_dev((unsigned*)(hF + (size_t)b * HD + col),
                   (unsigned)hb | ((unsigned)hob << 16));
      const unsigned short bb = f2bf(hn);
      const unsigned short bob = (unsigned short)__shfl_xor((int)bb, 1);
      habw[q] = (unsigned)bb | ((unsigned)bob << 16);
      habst[q] = b;
    }
    wave_signal(flagsB, ep, slot, lane);

    // ---- off-path: history write (plain), final-state write, xg swap ----
    #pragma unroll
    for (int q = 0; q < 4; ++q) {
      if (!(l15 & 1))
        st_u32_plain((unsigned*)(Habf + (size_t)(t * BA + habst[q]) * HD + col), habw[q]);
      if (t == SQ - 1) outT[col * BA + habst[q]] = hreg[q];
      xgR[q] = nR[q]; xgZ[q] = nZ[q]; xgH[q] = nH[q];
    }
  }
}

// ---------------- final output GEMM: Y = Habf @ W^T + b (256x256 tile, 8 waves, swizzled) -----
__global__ __launch_bounds__(512) void out_gemm_kernel(
    const unsigned short* __restrict__ A,  // 8192 x 512 bf16
    const float* __restrict__ Bw,          // 32000 x 512 f32
    const float* __restrict__ bias,        // 32000
    float* __restrict__ Y)                 // 8192 x 32000
{
  __shared__ unsigned short As[256 * 40];
  __shared__ unsigned short Bs[256 * 40];
  const int bid = blockIdx.x;
  const int s  = (bid & 7) * 500 + (bid >> 3);   // bijective XCD swizzle (4000 = 8*500)
  const int tm = s / 125, tn = s % 125;
  const int tid = threadIdx.x;
  const int wave = tid >> 6, lane = tid & 63;
  const int wm = wave >> 2, wn = wave & 3;
  const int l15 = lane & 15, lhi = lane >> 4;
  f32x4 acc[8][4] = {};

  for (int k0 = 0; k0 < 512; k0 += 32) {
    #pragma unroll
    for (int it = 0; it < 2; ++it) {
      const int c = tid + it * 512;              // 0..1023 chunks (256 rows x 4)
      const int row = c >> 2, c8 = (c & 3) << 3;
      *(uint4*)(As + row * 40 + c8) =
          *(const uint4*)(A + (size_t)(tm * 256 + row) * 512 + k0 + c8);
      const float4 b0 = *(const float4*)(Bw + (size_t)(tn * 256 + row) * 512 + k0 + c8);
      const float4 b1 = *(const float4*)(Bw + (size_t)(tn * 256 + row) * 512 + k0 + c8 + 4);
      union { unsigned short h[8]; uint4 u; } cv;
      cv.h[0] = f2bf(b0.x); cv.h[1] = f2bf(b0.y); cv.h[2] = f2bf(b0.z); cv.h[3] = f2bf(b0.w);
      cv.h[4] = f2bf(b1.x); cv.h[5] = f2bf(b1.y); cv.h[6] = f2bf(b1.z); cv.h[7] = f2bf(b1.w);
      *(uint4*)(Bs + row * 40 + c8) = cv.u;
    }
    __syncthreads();
    sh8 af[8], bf[4];
    #pragma unroll
    for (int mi = 0; mi < 8; ++mi)
      af[mi] = *(const sh8*)(As + (wm * 128 + mi * 16 + l15) * 40 + lhi * 8);
    #pragma unroll
    for (int ni = 0; ni < 4; ++ni)
      bf[ni] = *(const sh8*)(Bs + (wn * 64 + ni * 16 + l15) * 40 + lhi * 8);
    #pragma unroll
    for (int mi = 0; mi < 8; ++mi)
      #pragma unroll
      for (int ni = 0; ni < 4; ++ni)
        acc[mi][ni] = __builtin_amdgcn_mfma_f32_16x16x32_bf16(af[mi], bf[ni], acc[mi][ni], 0, 0, 0);
    __syncthreads();
  }

  #pragma unroll
  for (int ni = 0; ni < 4; ++ni) {
    const int colc = tn * 256 + wn * 64 + ni * 16 + l15;
    const float bv = bias[colc];
    #pragma unroll
    for (int mi = 0; mi < 8; ++mi) {
      const int row0 = tm * 256 + wm * 128 + mi * 16 + lhi * 4;
      #pragma unroll
      for (int q = 0; q < 4; ++q)
        Y[(size_t)(row0 + q) * VSZ + colc] = acc[mi][ni][q] + bv;
    }
  }
}

extern "C" void kernel_launch(void* const* d_in, const int* in_sizes, int n_in,
                              void* d_out, int out_size, void* d_ws, size_t ws_size,
                              hipStream_t stream)
{
  const int*   x   = (const int*)  d_in[0];
  const float* emb = (const float*)d_in[1];
  const float* Wr  = (const float*)d_in[2];
  const float* Br  = (const float*)d_in[3];
  const float* Wz  = (const float*)d_in[4];
  const float* Bz  = (const float*)d_in[5];
  const float* Wh  = (const float*)d_in[6];
  const float* Bh  = (const float*)d_in[7];
  const float* W   = (const float*)d_in[8];
  const float* bo  = (const float*)d_in[9];
  float* out = (float*)d_out;

  char* ws = (char*)d_ws;
  _Float16*       hF     = (_Float16*)(ws);                 //  64 KiB [64][512]
  _Float16*       uF     = (_Float16*)(ws + 65536);         //  64 KiB [64][512]
  unsigned*       flagsA = (unsigned*)(ws + 131072);        //  16 KiB (128 slots x 128B)
  unsigned*       flagsB = (unsigned*)(ws + 147456);        //  16 KiB
  unsigned short* Habf   = (unsigned short*)(ws + 163840);  //   8 MiB bf16 h history

  // XG (pre-projection) overlays d_out; dead before out_gemm writes Y.
  float* XG   = out;                  // [8192][1536]
  float* outT = out + 262144000ll;    // hT.T region

  // zero hF, uF, flags (deterministic across graph replays)
  (void)hipMemsetAsync(ws, 0, 163840, stream);

  proj_kernel<<<dim3(12, 64), 256, 0, stream>>>(x, emb, Wr, Br, Wz, Bz, Wh, Bh, XG);
  recur_kernel<<<NWG, 256, 0, stream>>>(XG, Wr, Wz, Wh, hF, uF, Habf, outT, flagsA, flagsB);
  out_gemm_kernel<<<4000, 512, 0, stream>>>(Habf, W, bo, out);
}

// Round 12
// 1721.548 us; speedup vs baseline: 3.6658x; 1.0847x over previous
//
#include <hip/hip_runtime.h>
#include <cstdint>
#include <cstddef>

#define VSZ 32000
#define ED  512
#define HD  512
#define SQ  128
#define BA  64
#define INW 1024
#define NG  1536
#define NWG 32
#define FLG 32   // flag stride in dwords (one 128B line per wave-slot)

typedef __attribute__((ext_vector_type(8))) short sh8;
typedef __attribute__((ext_vector_type(4))) float f32x4;
typedef _Float16 half8 __attribute__((ext_vector_type(8)));
typedef unsigned u32x4 __attribute__((ext_vector_type(4)));

__device__ inline unsigned short f2bf(float f) {
  unsigned int u = __float_as_uint(f);
  u += 0x7fffu + ((u >> 16) & 1u);
  return (unsigned short)(u >> 16);
}

// Device-scope 16B load (bypass L1+L2, read at L3 coherence point). Burst-issue,
// then ONE s_waitcnt vmcnt(0) + sched_barrier(0) before consuming.
__device__ __forceinline__ half8 ld_h8_dev(const _Float16* p) {
  u32x4 r;
  asm volatile("global_load_dwordx4 %0, %1, off sc0 sc1" : "=v"(r) : "v"(p));
  return __builtin_bit_cast(half8, r);
}

__device__ __forceinline__ void st_u32_dev(unsigned* p, unsigned v) {
  asm volatile("global_store_dword %0, %1, off sc0 sc1" :: "v"(p), "v"(v) : "memory");
}

__device__ __forceinline__ void st_u32_plain(unsigned* p, unsigned v) {
  asm volatile("global_store_dword %0, %1, off" :: "v"(p), "v"(v) : "memory");
}

__device__ __forceinline__ unsigned ld_u32_dev(const unsigned* p) {
  unsigned r;
  asm volatile("global_load_dword %0, %1, off sc0 sc1" : "=v"(r) : "v"(p));
  asm volatile("s_waitcnt vmcnt(0)" ::: "memory");
  __builtin_amdgcn_sched_barrier(0);
  return r;
}

// Wave-autonomous signal: drain this wave's device-scope data stores, then
// publish epoch. sched_barrier keeps later compute from hoisting above.
__device__ __forceinline__ void wave_signal(unsigned* flags, unsigned epoch, int slot, int lane) {
  asm volatile("s_waitcnt vmcnt(0)" ::: "memory");
  if (lane == 0) st_u32_dev(flags + slot * FLG, epoch);
  __builtin_amdgcn_sched_barrier(0);
}

// Wave-autonomous wait: lane l polls producer-WG (l&31)'s wave-wv flag.
__device__ __forceinline__ void wave_wait(const unsigned* flags, unsigned epoch, int wv, int lane) {
  const unsigned* fp = flags + (((lane & 31) << 2) + wv) * FLG;
  unsigned v = ld_u32_dev(fp);
  while (!__all((int)(v >= epoch))) v = ld_u32_dev(fp);
}

// ---------------- pre-projection (fp16 MFMA): XG = emb[x] @ {Wr,Wz,Wh}[:,:512]^T + bias ------
__global__ __launch_bounds__(256) void proj_kernel(
    const int* __restrict__ x, const float* __restrict__ emb,
    const float* __restrict__ Wr, const float* __restrict__ Br,
    const float* __restrict__ Wz, const float* __restrict__ Bz,
    const float* __restrict__ Wh, const float* __restrict__ Bh,
    float* __restrict__ XG)
{
  __shared__ _Float16 As[128 * 40];
  __shared__ _Float16 Bs[128 * 40];
  const int tn = blockIdx.x;           // 0..11 (N tile; gate = tn>>2, no straddle)
  const int tm = blockIdx.y;           // 0..63 (M tile)
  const int g  = tn >> 2;
  const float* Wsrc = (g == 0 ? Wr : (g == 1 ? Wz : Wh));
  const float* Bias = (g == 0 ? Br : (g == 1 ? Bz : Bh));
  const int jj0 = (tn & 3) * 128;      // row base within the gate's weight matrix
  const int tid = threadIdx.x;
  const int wave = tid >> 6, lane = tid & 63;
  const int wm = wave >> 1, wn = wave & 1;
  const int l15 = lane & 15, lhi = lane >> 4;
  f32x4 acc[4][4] = {};

  for (int k0 = 0; k0 < ED; k0 += 32) {
    #pragma unroll
    for (int it = 0; it < 2; ++it) {
      const int c = tid + it * 256;            // 0..511 chunks (128 rows x 4)
      const int row = c >> 2, c8 = (c & 3) << 3;
      {
        const int src = x[tm * 128 + row];
        const float4 a0 = *(const float4*)(emb + (size_t)src * ED + k0 + c8);
        const float4 a1 = *(const float4*)(emb + (size_t)src * ED + k0 + c8 + 4);
        half8 w;
        w[0]=(_Float16)a0.x; w[1]=(_Float16)a0.y; w[2]=(_Float16)a0.z; w[3]=(_Float16)a0.w;
        w[4]=(_Float16)a1.x; w[5]=(_Float16)a1.y; w[6]=(_Float16)a1.z; w[7]=(_Float16)a1.w;
        *(half8*)(As + row * 40 + c8) = w;
      }
      {
        const float* wr = Wsrc + (size_t)(jj0 + row) * INW + k0 + c8;
        const float4 b0 = *(const float4*)(wr);
        const float4 b1 = *(const float4*)(wr + 4);
        half8 w;
        w[0]=(_Float16)b0.x; w[1]=(_Float16)b0.y; w[2]=(_Float16)b0.z; w[3]=(_Float16)b0.w;
        w[4]=(_Float16)b1.x; w[5]=(_Float16)b1.y; w[6]=(_Float16)b1.z; w[7]=(_Float16)b1.w;
        *(half8*)(Bs + row * 40 + c8) = w;
      }
    }
    __syncthreads();
    half8 af[4], bf[4];
    #pragma unroll
    for (int mi = 0; mi < 4; ++mi)
      af[mi] = *(const half8*)(As + (wm * 64 + mi * 16 + l15) * 40 + lhi * 8);
    #pragma unroll
    for (int ni = 0; ni < 4; ++ni)
      bf[ni] = *(const half8*)(Bs + (wn * 64 + ni * 16 + l15) * 40 + lhi * 8);
    #pragma unroll
    for (int mi = 0; mi < 4; ++mi)
      #pragma unroll
      for (int ni = 0; ni < 4; ++ni)
        acc[mi][ni] = __builtin_amdgcn_mfma_f32_16x16x32_f16(af[mi], bf[ni], acc[mi][ni], 0, 0, 0);
    __syncthreads();
  }
  #pragma unroll
  for (int ni = 0; ni < 4; ++ni) {
    const int jc = tn * 128 + wn * 64 + ni * 16 + l15;
    const float bv = Bias[jj0 + wn * 64 + ni * 16 + l15];
    #pragma unroll
    for (int mi = 0; mi < 4; ++mi) {
      const int m0 = tm * 128 + wm * 64 + mi * 16 + lhi * 4;
      #pragma unroll
      for (int q = 0; q < 4; ++q)
        XG[(size_t)(m0 + q) * NG + jc] = acc[mi][ni][q] + bv;
    }
  }
}

// ---------------- persistent GRU recurrence (wave-autonomous flags, no __syncthreads) --------
__global__ __launch_bounds__(256) void recur_kernel(
    const float* __restrict__ XG,     // [8192][1536]
    const float* __restrict__ Wr, const float* __restrict__ Wz, const float* __restrict__ Wh,
    _Float16* __restrict__ hF,        // [64][512] fp16 (device-coherent)
    _Float16* __restrict__ uF,        // [64][512] fp16 (device-coherent, r*h)
    unsigned short* __restrict__ Habf,// [8192][512] bf16
    float* __restrict__ outT,         // [512][64]  (hT.T)
    unsigned* __restrict__ flagsA,
    unsigned* __restrict__ flagsB)
{
  const int tid = threadIdx.x, wg = blockIdx.x;
  const int wv = tid >> 6, lane = tid & 63;
  const int l15 = lane & 15, lhi = lane >> 4;
  const int mrow = wv * 16 + l15;          // A-fragment row (batch)
  const int col  = wg * 16 + l15;          // owned column (same for r, z, h_cand)
  const int slot = wg * 4 + wv;

  // ---- weight B-fragments in registers (fp16), loaded once ----
  half8 wfR[16], wfZ[16], wfH[16];
  {
    const float* WR = Wr + (size_t)col * INW + ED + lhi * 8;
    const float* WZ = Wz + (size_t)col * INW + ED + lhi * 8;
    const float* WH = Wh + (size_t)col * INW + ED + lhi * 8;
    #pragma unroll
    for (int s = 0; s < 16; ++s) {
      float4 a, b; half8 w;
      a = *(const float4*)(WR + s * 32); b = *(const float4*)(WR + s * 32 + 4);
      w[0]=(_Float16)a.x; w[1]=(_Float16)a.y; w[2]=(_Float16)a.z; w[3]=(_Float16)a.w;
      w[4]=(_Float16)b.x; w[5]=(_Float16)b.y; w[6]=(_Float16)b.z; w[7]=(_Float16)b.w;
      wfR[s] = w;
      a = *(const float4*)(WZ + s * 32); b = *(const float4*)(WZ + s * 32 + 4);
      w[0]=(_Float16)a.x; w[1]=(_Float16)a.y; w[2]=(_Float16)a.z; w[3]=(_Float16)a.w;
      w[4]=(_Float16)b.x; w[5]=(_Float16)b.y; w[6]=(_Float16)b.z; w[7]=(_Float16)b.w;
      wfZ[s] = w;
      a = *(const float4*)(WH + s * 32); b = *(const float4*)(WH + s * 32 + 4);
      w[0]=(_Float16)a.x; w[1]=(_Float16)a.y; w[2]=(_Float16)a.z; w[3]=(_Float16)a.w;
      w[4]=(_Float16)b.x; w[5]=(_Float16)b.y; w[6]=(_Float16)b.z; w[7]=(_Float16)b.w;
      wfH[s] = w;
    }
  }

  // per-thread GRU state (same (b,col) handled by this thread in both phases)
  float hreg[4] = {0.f, 0.f, 0.f, 0.f};
  float zreg[4];
  // XG for step 0
  float xgR[4], xgZ[4], xgH[4];
  #pragma unroll
  for (int q = 0; q < 4; ++q) {
    const int b = wv * 16 + lhi * 4 + q;
    const float* xp = XG + (size_t)b * NG + col;
    xgR[q] = xp[0]; xgZ[q] = xp[512]; xgH[q] = xp[1024];
  }

  for (int t = 0; t < SQ; ++t) {
    const unsigned ep = (unsigned)(t + 1);
    // ---- wait for h of step t (phase B of t-1); t=0 passes trivially ----
    wave_wait(flagsB, (unsigned)t, wv, lane);

    // ---- phase A critical path: load h, R-GEMM, u = sigmoid(preR)*h, store+signal ----
    half8 ha[16];
    #pragma unroll
    for (int s = 0; s < 16; ++s)
      ha[s] = ld_h8_dev(hF + (size_t)mrow * HD + s * 32 + lhi * 8);
    asm volatile("s_waitcnt vmcnt(0)" ::: "memory");
    __builtin_amdgcn_sched_barrier(0);

    f32x4 accR = {};
    #pragma unroll
    for (int s = 0; s < 16; ++s)
      accR = __builtin_amdgcn_mfma_f32_16x16x32_f16(ha[s], wfR[s], accR, 0, 0, 0);
    #pragma unroll
    for (int q = 0; q < 4; ++q) {
      const int b = wv * 16 + lhi * 4 + q;
      const float r = 1.0f / (1.0f + __expf(-(accR[q] + xgR[q])));
      const _Float16 uh = (_Float16)(r * hreg[q]);
      const unsigned short ub = __builtin_bit_cast(unsigned short, uh);
      const unsigned short ob = (unsigned short)__shfl_xor((int)ub, 1);
      if (!(l15 & 1))
        st_u32_dev((unsigned*)(uF + (size_t)b * HD + col),
                   (unsigned)ub | ((unsigned)ob << 16));
    }
    wave_signal(flagsA, ep, slot, lane);

    // ---- off-path: Z-GEMM + z sigmoid + next-step XG prefetch (hides propagation) ----
    f32x4 accZ = {};
    #pragma unroll
    for (int s = 0; s < 16; ++s)
      accZ = __builtin_amdgcn_mfma_f32_16x16x32_f16(ha[s], wfZ[s], accZ, 0, 0, 0);
    float nR[4] = {0,0,0,0}, nZ[4] = {0,0,0,0}, nH[4] = {0,0,0,0};
    if (t + 1 < SQ) {
      #pragma unroll
      for (int q = 0; q < 4; ++q) {
        const int b = wv * 16 + lhi * 4 + q;
        const float* xp = XG + (size_t)(t + 1) * BA * NG + (size_t)b * NG + col;
        nR[q] = xp[0]; nZ[q] = xp[512]; nH[q] = xp[1024];
      }
    }
    #pragma unroll
    for (int q = 0; q < 4; ++q)
      zreg[q] = 1.0f / (1.0f + __expf(-(accZ[q] + xgZ[q])));

    // ---- phase B: wait u, H-GEMM, combine, store h + signal ----
    wave_wait(flagsA, ep, wv, lane);
    half8 ua[16];
    #pragma unroll
    for (int s = 0; s < 16; ++s)
      ua[s] = ld_h8_dev(uF + (size_t)mrow * HD + s * 32 + lhi * 8);
    asm volatile("s_waitcnt vmcnt(0)" ::: "memory");
    __builtin_amdgcn_sched_barrier(0);
    f32x4 acc = {};
    #pragma unroll
    for (int s = 0; s < 16; ++s)
      acc = __builtin_amdgcn_mfma_f32_16x16x32_f16(ua[s], wfH[s], acc, 0, 0, 0);

    unsigned habw[4]; int habst[4];
    #pragma unroll
    for (int q = 0; q < 4; ++q) {
      const int b = wv * 16 + lhi * 4 + q;
      const float e  = __expf(2.0f * (acc[q] + xgH[q]));   // tanh, inf-safe
      const float hc = 1.0f - 2.0f / (e + 1.0f);
      const float hn = zreg[q] * hreg[q] + (1.0f - zreg[q]) * hc;
      hreg[q] = hn;
      const _Float16 hh = (_Float16)hn;
      const unsigned short hb = __builtin_bit_cast(unsigned short, hh);
      const unsigned short hob = (unsigned short)__shfl_xor((int)hb, 1);
      if (!(l15 & 1))
        st_u32_dev((unsigned*)(hF + (size_t)b * HD + col),
                   (unsigned)hb | ((unsigned)hob << 16));
      const unsigned short bb = f2bf(hn);
      const unsigned short bob = (unsigned short)__shfl_xor((int)bb, 1);
      habw[q] = (unsigned)bb | ((unsigned)bob << 16);
      habst[q] = b;
    }
    wave_signal(flagsB, ep, slot, lane);

    // ---- off-path: history write (plain), final-state write, xg swap ----
    #pragma unroll
    for (int q = 0; q < 4; ++q) {
      if (!(l15 & 1))
        st_u32_plain((unsigned*)(Habf + (size_t)(t * BA + habst[q]) * HD + col), habw[q]);
      if (t == SQ - 1) outT[col * BA + habst[q]] = hreg[q];
      xgR[q] = nR[q]; xgZ[q] = nZ[q]; xgH[q] = nH[q];
    }
  }
}

// ---------------- final output GEMM: Y = Habf @ W^T + b (m97-style 128x128, 4 waves) ----------
// XCD swizzle oriented for B-panel reuse: consecutive blocks on an XCD share tn.
__global__ __launch_bounds__(256) void out_gemm_kernel(
    const unsigned short* __restrict__ A,  // 8192 x 512 bf16
    const float* __restrict__ Bw,          // 32000 x 512 f32
    const float* __restrict__ bias,        // 32000
    float* __restrict__ Y)                 // 8192 x 32000
{
  __shared__ unsigned short As[128 * 32];
  __shared__ unsigned short Bs[128 * 32];
  const int bid = blockIdx.x;
  const int s  = (bid & 7) * 2000 + (bid >> 3);  // bijective (16000 = 8*2000)
  const int tn = s >> 6, tm = s & 63;            // same-XCD neighbors share tn (B-panel)
  const int tid = threadIdx.x;
  const int wave = tid >> 6, lane = tid & 63;
  const int wm = wave >> 1, wn = wave & 1;
  const int l15 = lane & 15, lhi = lane >> 4;
  f32x4 acc[4][4] = {};

  for (int k0 = 0; k0 < 512; k0 += 32) {
    #pragma unroll
    for (int it = 0; it < 2; ++it) {
      const int ss  = tid + it * 256;
      const int row = ss >> 2;
      const int c8  = (ss & 3) << 3;
      *(uint4*)(As + row * 32 + c8) =
          *(const uint4*)(A + (size_t)(tm * 128 + row) * 512 + k0 + c8);
      const float4 b0 = *(const float4*)(Bw + (size_t)(tn * 128 + row) * 512 + k0 + c8);
      const float4 b1 = *(const float4*)(Bw + (size_t)(tn * 128 + row) * 512 + k0 + c8 + 4);
      union { unsigned short h[8]; uint4 u; } cv;
      cv.h[0] = f2bf(b0.x); cv.h[1] = f2bf(b0.y); cv.h[2] = f2bf(b0.z); cv.h[3] = f2bf(b0.w);
      cv.h[4] = f2bf(b1.x); cv.h[5] = f2bf(b1.y); cv.h[6] = f2bf(b1.z); cv.h[7] = f2bf(b1.w);
      *(uint4*)(Bs + row * 32 + c8) = cv.u;
    }
    __syncthreads();
    sh8 af[4], bfr[4];
    #pragma unroll
    for (int mi = 0; mi < 4; ++mi)
      af[mi] = *(const sh8*)(As + (wm * 64 + mi * 16 + l15) * 32 + lhi * 8);
    #pragma unroll
    for (int ni = 0; ni < 4; ++ni)
      bfr[ni] = *(const sh8*)(Bs + (wn * 64 + ni * 16 + l15) * 32 + lhi * 8);
    #pragma unroll
    for (int mi = 0; mi < 4; ++mi)
      #pragma unroll
      for (int ni = 0; ni < 4; ++ni)
        acc[mi][ni] = __builtin_amdgcn_mfma_f32_16x16x32_bf16(af[mi], bfr[ni], acc[mi][ni], 0, 0, 0);
    __syncthreads();
  }

  #pragma unroll
  for (int ni = 0; ni < 4; ++ni) {
    const int col = tn * 128 + wn * 64 + ni * 16 + l15;
    const float bv = bias[col];
    #pragma unroll
    for (int mi = 0; mi < 4; ++mi) {
      const int row0 = tm * 128 + wm * 64 + mi * 16 + lhi * 4;
      #pragma unroll
      for (int q = 0; q < 4; ++q)
        Y[(size_t)(row0 + q) * VSZ + col] = acc[mi][ni][q] + bv;
    }
  }
}

extern "C" void kernel_launch(void* const* d_in, const int* in_sizes, int n_in,
                              void* d_out, int out_size, void* d_ws, size_t ws_size,
                              hipStream_t stream)
{
  const int*   x   = (const int*)  d_in[0];
  const float* emb = (const float*)d_in[1];
  const float* Wr  = (const float*)d_in[2];
  const float* Br  = (const float*)d_in[3];
  const float* Wz  = (const float*)d_in[4];
  const float* Bz  = (const float*)d_in[5];
  const float* Wh  = (const float*)d_in[6];
  const float* Bh  = (const float*)d_in[7];
  const float* W   = (const float*)d_in[8];
  const float* bo  = (const float*)d_in[9];
  float* out = (float*)d_out;

  char* ws = (char*)d_ws;
  _Float16*       hF     = (_Float16*)(ws);                 //  64 KiB [64][512]
  _Float16*       uF     = (_Float16*)(ws + 65536);         //  64 KiB [64][512]
  unsigned*       flagsA = (unsigned*)(ws + 131072);        //  16 KiB (128 slots x 128B)
  unsigned*       flagsB = (unsigned*)(ws + 147456);        //  16 KiB
  unsigned short* Habf   = (unsigned short*)(ws + 163840);  //   8 MiB bf16 h history

  // XG (pre-projection) overlays d_out; dead before out_gemm writes Y.
  float* XG   = out;                  // [8192][1536]
  float* outT = out + 262144000ll;    // hT.T region

  // zero hF, uF, flags (deterministic across graph replays)
  (void)hipMemsetAsync(ws, 0, 163840, stream);

  proj_kernel<<<dim3(12, 64), 256, 0, stream>>>(x, emb, Wr, Br, Wz, Bz, Wh, Bh, XG);
  recur_kernel<<<NWG, 256, 0, stream>>>(XG, Wr, Wz, Wh, hF, uF, Habf, outT, flagsA, flagsB);
  out_gemm_kernel<<<16000, 256, 0, stream>>>(Habf, W, bo, out);
}

// Round 13
// 1615.459 us; speedup vs baseline: 3.9065x; 1.0657x over previous
//
#include <hip/hip_runtime.h>
#include <cstdint>
#include <cstddef>

#define VSZ 32000
#define ED  512
#define HD  512
#define SQ  128
#define BA  64
#define INW 1024
#define NG  1536
#define NWG 32
#define FLG 32   // flag stride in dwords (one 128B line per wave-slot)

typedef __attribute__((ext_vector_type(8))) short sh8;
typedef __attribute__((ext_vector_type(4))) float f32x4;
typedef _Float16 half8 __attribute__((ext_vector_type(8)));
typedef unsigned u32x4 __attribute__((ext_vector_type(4)));

typedef __attribute__((address_space(1))) const void glob_cv;
typedef __attribute__((address_space(3))) void lds_v;

__device__ inline unsigned short f2bf(float f) {
  unsigned int u = __float_as_uint(f);
  u += 0x7fffu + ((u >> 16) & 1u);
  return (unsigned short)(u >> 16);
}

// Device-scope 16B load (bypass L1+L2, read at L3 coherence point). Burst-issue,
// then ONE s_waitcnt vmcnt(0) + sched_barrier(0) before consuming.
__device__ __forceinline__ half8 ld_h8_dev(const _Float16* p) {
  u32x4 r;
  asm volatile("global_load_dwordx4 %0, %1, off sc0 sc1" : "=v"(r) : "v"(p));
  return __builtin_bit_cast(half8, r);
}

__device__ __forceinline__ void st_u32_dev(unsigned* p, unsigned v) {
  asm volatile("global_store_dword %0, %1, off sc0 sc1" :: "v"(p), "v"(v) : "memory");
}

__device__ __forceinline__ void st_u32_plain(unsigned* p, unsigned v) {
  asm volatile("global_store_dword %0, %1, off" :: "v"(p), "v"(v) : "memory");
}

__device__ __forceinline__ unsigned ld_u32_dev(const unsigned* p) {
  unsigned r;
  asm volatile("global_load_dword %0, %1, off sc0 sc1" : "=v"(r) : "v"(p));
  asm volatile("s_waitcnt vmcnt(0)" ::: "memory");
  __builtin_amdgcn_sched_barrier(0);
  return r;
}

// Wave-autonomous signal: drain this wave's device-scope data stores, then
// publish epoch. sched_barrier keeps later compute from hoisting above.
__device__ __forceinline__ void wave_signal(unsigned* flags, unsigned epoch, int slot, int lane) {
  asm volatile("s_waitcnt vmcnt(0)" ::: "memory");
  if (lane == 0) st_u32_dev(flags + slot * FLG, epoch);
  __builtin_amdgcn_sched_barrier(0);
}

// Wave-autonomous wait: lane l polls producer-WG (l&31)'s wave-wv flag.
__device__ __forceinline__ void wave_wait(const unsigned* flags, unsigned epoch, int wv, int lane) {
  const unsigned* fp = flags + (((lane & 31) << 2) + wv) * FLG;
  unsigned v = ld_u32_dev(fp);
  while (!__all((int)(v >= epoch))) v = ld_u32_dev(fp);
}

// ---------------- pre-projection (fp16 MFMA): XG = emb[x] @ {Wr,Wz,Wh}[:,:512]^T + bias ------
__global__ __launch_bounds__(256) void proj_kernel(
    const int* __restrict__ x, const float* __restrict__ emb,
    const float* __restrict__ Wr, const float* __restrict__ Br,
    const float* __restrict__ Wz, const float* __restrict__ Bz,
    const float* __restrict__ Wh, const float* __restrict__ Bh,
    float* __restrict__ XG)
{
  __shared__ _Float16 As[128 * 40];
  __shared__ _Float16 Bs[128 * 40];
  const int tn = blockIdx.x;           // 0..11 (N tile; gate = tn>>2, no straddle)
  const int tm = blockIdx.y;           // 0..63 (M tile)
  const int g  = tn >> 2;
  const float* Wsrc = (g == 0 ? Wr : (g == 1 ? Wz : Wh));
  const float* Bias = (g == 0 ? Br : (g == 1 ? Bz : Bh));
  const int jj0 = (tn & 3) * 128;      // row base within the gate's weight matrix
  const int tid = threadIdx.x;
  const int wave = tid >> 6, lane = tid & 63;
  const int wm = wave >> 1, wn = wave & 1;
  const int l15 = lane & 15, lhi = lane >> 4;
  f32x4 acc[4][4] = {};

  for (int k0 = 0; k0 < ED; k0 += 32) {
    #pragma unroll
    for (int it = 0; it < 2; ++it) {
      const int c = tid + it * 256;            // 0..511 chunks (128 rows x 4)
      const int row = c >> 2, c8 = (c & 3) << 3;
      {
        const int src = x[tm * 128 + row];
        const float4 a0 = *(const float4*)(emb + (size_t)src * ED + k0 + c8);
        const float4 a1 = *(const float4*)(emb + (size_t)src * ED + k0 + c8 + 4);
        half8 w;
        w[0]=(_Float16)a0.x; w[1]=(_Float16)a0.y; w[2]=(_Float16)a0.z; w[3]=(_Float16)a0.w;
        w[4]=(_Float16)a1.x; w[5]=(_Float16)a1.y; w[6]=(_Float16)a1.z; w[7]=(_Float16)a1.w;
        *(half8*)(As + row * 40 + c8) = w;
      }
      {
        const float* wr = Wsrc + (size_t)(jj0 + row) * INW + k0 + c8;
        const float4 b0 = *(const float4*)(wr);
        const float4 b1 = *(const float4*)(wr + 4);
        half8 w;
        w[0]=(_Float16)b0.x; w[1]=(_Float16)b0.y; w[2]=(_Float16)b0.z; w[3]=(_Float16)b0.w;
        w[4]=(_Float16)b1.x; w[5]=(_Float16)b1.y; w[6]=(_Float16)b1.z; w[7]=(_Float16)b1.w;
        *(half8*)(Bs + row * 40 + c8) = w;
      }
    }
    __syncthreads();
    half8 af[4], bf[4];
    #pragma unroll
    for (int mi = 0; mi < 4; ++mi)
      af[mi] = *(const half8*)(As + (wm * 64 + mi * 16 + l15) * 40 + lhi * 8);
    #pragma unroll
    for (int ni = 0; ni < 4; ++ni)
      bf[ni] = *(const half8*)(Bs + (wn * 64 + ni * 16 + l15) * 40 + lhi * 8);
    #pragma unroll
    for (int mi = 0; mi < 4; ++mi)
      #pragma unroll
      for (int ni = 0; ni < 4; ++ni)
        acc[mi][ni] = __builtin_amdgcn_mfma_f32_16x16x32_f16(af[mi], bf[ni], acc[mi][ni], 0, 0, 0);
    __syncthreads();
  }
  #pragma unroll
  for (int ni = 0; ni < 4; ++ni) {
    const int jc = tn * 128 + wn * 64 + ni * 16 + l15;
    const float bv = Bias[jj0 + wn * 64 + ni * 16 + l15];
    #pragma unroll
    for (int mi = 0; mi < 4; ++mi) {
      const int m0 = tm * 128 + wm * 64 + mi * 16 + lhi * 4;
      #pragma unroll
      for (int q = 0; q < 4; ++q)
        XG[(size_t)(m0 + q) * NG + jc] = acc[mi][ni][q] + bv;
    }
  }
}

// ---------------- persistent GRU recurrence (wave-autonomous flags, no __syncthreads) --------
__global__ __launch_bounds__(256) void recur_kernel(
    const float* __restrict__ XG,     // [8192][1536]
    const float* __restrict__ Wr, const float* __restrict__ Wz, const float* __restrict__ Wh,
    _Float16* __restrict__ hF,        // [64][512] fp16 (device-coherent)
    _Float16* __restrict__ uF,        // [64][512] fp16 (device-coherent, r*h)
    unsigned short* __restrict__ Habf,// [8192][512] bf16
    float* __restrict__ outT,         // [512][64]  (hT.T)
    unsigned* __restrict__ flagsA,
    unsigned* __restrict__ flagsB)
{
  const int tid = threadIdx.x, wg = blockIdx.x;
  const int wv = tid >> 6, lane = tid & 63;
  const int l15 = lane & 15, lhi = lane >> 4;
  const int mrow = wv * 16 + l15;          // A-fragment row (batch)
  const int col  = wg * 16 + l15;          // owned column (same for r, z, h_cand)
  const int slot = wg * 4 + wv;

  // ---- weight B-fragments in registers (fp16), loaded once ----
  half8 wfR[16], wfZ[16], wfH[16];
  {
    const float* WR = Wr + (size_t)col * INW + ED + lhi * 8;
    const float* WZ = Wz + (size_t)col * INW + ED + lhi * 8;
    const float* WH = Wh + (size_t)col * INW + ED + lhi * 8;
    #pragma unroll
    for (int s = 0; s < 16; ++s) {
      float4 a, b; half8 w;
      a = *(const float4*)(WR + s * 32); b = *(const float4*)(WR + s * 32 + 4);
      w[0]=(_Float16)a.x; w[1]=(_Float16)a.y; w[2]=(_Float16)a.z; w[3]=(_Float16)a.w;
      w[4]=(_Float16)b.x; w[5]=(_Float16)b.y; w[6]=(_Float16)b.z; w[7]=(_Float16)b.w;
      wfR[s] = w;
      a = *(const float4*)(WZ + s * 32); b = *(const float4*)(WZ + s * 32 + 4);
      w[0]=(_Float16)a.x; w[1]=(_Float16)a.y; w[2]=(_Float16)a.z; w[3]=(_Float16)a.w;
      w[4]=(_Float16)b.x; w[5]=(_Float16)b.y; w[6]=(_Float16)b.z; w[7]=(_Float16)b.w;
      wfZ[s] = w;
      a = *(const float4*)(WH + s * 32); b = *(const float4*)(WH + s * 32 + 4);
      w[0]=(_Float16)a.x; w[1]=(_Float16)a.y; w[2]=(_Float16)a.z; w[3]=(_Float16)a.w;
      w[4]=(_Float16)b.x; w[5]=(_Float16)b.y; w[6]=(_Float16)b.z; w[7]=(_Float16)b.w;
      wfH[s] = w;
    }
  }

  // per-thread GRU state (same (b,col) handled by this thread in both phases)
  float hreg[4] = {0.f, 0.f, 0.f, 0.f};
  float zreg[4];
  // XG for step 0
  float xgR[4], xgZ[4], xgH[4];
  #pragma unroll
  for (int q = 0; q < 4; ++q) {
    const int b = wv * 16 + lhi * 4 + q;
    const float* xp = XG + (size_t)b * NG + col;
    xgR[q] = xp[0]; xgZ[q] = xp[512]; xgH[q] = xp[1024];
  }

  for (int t = 0; t < SQ; ++t) {
    const unsigned ep = (unsigned)(t + 1);
    // ---- wait for h of step t (phase B of t-1); t=0 passes trivially ----
    wave_wait(flagsB, (unsigned)t, wv, lane);

    // ---- phase A critical path: load h, R-GEMM, u = sigmoid(preR)*h, store+signal ----
    half8 ha[16];
    #pragma unroll
    for (int s = 0; s < 16; ++s)
      ha[s] = ld_h8_dev(hF + (size_t)mrow * HD + s * 32 + lhi * 8);
    asm volatile("s_waitcnt vmcnt(0)" ::: "memory");
    __builtin_amdgcn_sched_barrier(0);

    f32x4 accR = {};
    #pragma unroll
    for (int s = 0; s < 16; ++s)
      accR = __builtin_amdgcn_mfma_f32_16x16x32_f16(ha[s], wfR[s], accR, 0, 0, 0);
    #pragma unroll
    for (int q = 0; q < 4; ++q) {
      const int b = wv * 16 + lhi * 4 + q;
      const float r = 1.0f / (1.0f + __expf(-(accR[q] + xgR[q])));
      const _Float16 uh = (_Float16)(r * hreg[q]);
      const unsigned short ub = __builtin_bit_cast(unsigned short, uh);
      const unsigned short ob = (unsigned short)__shfl_xor((int)ub, 1);
      if (!(l15 & 1))
        st_u32_dev((unsigned*)(uF + (size_t)b * HD + col),
                   (unsigned)ub | ((unsigned)ob << 16));
    }
    wave_signal(flagsA, ep, slot, lane);

    // ---- off-path: Z-GEMM + z sigmoid + next-step XG prefetch (hides propagation) ----
    f32x4 accZ = {};
    #pragma unroll
    for (int s = 0; s < 16; ++s)
      accZ = __builtin_amdgcn_mfma_f32_16x16x32_f16(ha[s], wfZ[s], accZ, 0, 0, 0);
    float nR[4] = {0,0,0,0}, nZ[4] = {0,0,0,0}, nH[4] = {0,0,0,0};
    if (t + 1 < SQ) {
      #pragma unroll
      for (int q = 0; q < 4; ++q) {
        const int b = wv * 16 + lhi * 4 + q;
        const float* xp = XG + (size_t)(t + 1) * BA * NG + (size_t)b * NG + col;
        nR[q] = xp[0]; nZ[q] = xp[512]; nH[q] = xp[1024];
      }
    }
    #pragma unroll
    for (int q = 0; q < 4; ++q)
      zreg[q] = 1.0f / (1.0f + __expf(-(accZ[q] + xgZ[q])));

    // ---- phase B: wait u, H-GEMM, combine, store h + signal ----
    wave_wait(flagsA, ep, wv, lane);
    half8 ua[16];
    #pragma unroll
    for (int s = 0; s < 16; ++s)
      ua[s] = ld_h8_dev(uF + (size_t)mrow * HD + s * 32 + lhi * 8);
    asm volatile("s_waitcnt vmcnt(0)" ::: "memory");
    __builtin_amdgcn_sched_barrier(0);
    f32x4 acc = {};
    #pragma unroll
    for (int s = 0; s < 16; ++s)
      acc = __builtin_amdgcn_mfma_f32_16x16x32_f16(ua[s], wfH[s], acc, 0, 0, 0);

    unsigned habw[4]; int habst[4];
    #pragma unroll
    for (int q = 0; q < 4; ++q) {
      const int b = wv * 16 + lhi * 4 + q;
      const float e  = __expf(2.0f * (acc[q] + xgH[q]));   // tanh, inf-safe
      const float hc = 1.0f - 2.0f / (e + 1.0f);
      const float hn = zreg[q] * hreg[q] + (1.0f - zreg[q]) * hc;
      hreg[q] = hn;
      const _Float16 hh = (_Float16)hn;
      const unsigned short hb = __builtin_bit_cast(unsigned short, hh);
      const unsigned short hob = (unsigned short)__shfl_xor((int)hb, 1);
      if (!(l15 & 1))
        st_u32_dev((unsigned*)(hF + (size_t)b * HD + col),
                   (unsigned)hb | ((unsigned)hob << 16));
      const unsigned short bb = f2bf(hn);
      const unsigned short bob = (unsigned short)__shfl_xor((int)bb, 1);
      habw[q] = (unsigned)bb | ((unsigned)bob << 16);
      habst[q] = b;
    }
    wave_signal(flagsB, ep, slot, lane);

    // ---- off-path: history write (plain), final-state write, xg swap ----
    #pragma unroll
    for (int q = 0; q < 4; ++q) {
      if (!(l15 & 1))
        st_u32_plain((unsigned*)(Habf + (size_t)(t * BA + habst[q]) * HD + col), habw[q]);
      if (t == SQ - 1) outT[col * BA + habst[q]] = hreg[q];
      xgR[q] = nR[q]; xgZ[q] = nZ[q]; xgH[q] = nH[q];
    }
  }
}

// ---------------- W f32 -> bf16 one-shot conversion ------------------------------------------
__global__ __launch_bounds__(256) void wconv_kernel(const float* __restrict__ W,
                                                    unsigned short* __restrict__ Wbf)
{
  const size_t i = ((size_t)blockIdx.x * 256 + threadIdx.x) * 8;   // 16.384M elems
  const float4 a = *(const float4*)(W + i);
  const float4 b = *(const float4*)(W + i + 4);
  union { unsigned short h[8]; uint4 u; } cv;
  cv.h[0] = f2bf(a.x); cv.h[1] = f2bf(a.y); cv.h[2] = f2bf(a.z); cv.h[3] = f2bf(a.w);
  cv.h[4] = f2bf(b.x); cv.h[5] = f2bf(b.y); cv.h[6] = f2bf(b.z); cv.h[7] = f2bf(b.w);
  *(uint4*)(Wbf + i) = cv.u;
}

// ---------------- out GEMM, bf16 x bf16, global_load_lds staging (m97 step-3 structure) -------
__global__ __launch_bounds__(256) void out_gemm_gll_kernel(
    const unsigned short* __restrict__ A,   // 8192 x 512 bf16
    const unsigned short* __restrict__ Bw,  // 32000 x 512 bf16
    const float* __restrict__ bias,         // 32000
    float* __restrict__ Y)                  // 8192 x 32000
{
  __shared__ unsigned short As[128 * 32];
  __shared__ unsigned short Bs[128 * 32];
  const int bid = blockIdx.x;
  const int s  = (bid & 7) * 2000 + (bid >> 3);  // bijective (16000 = 8*2000)
  const int tn = s >> 6, tm = s & 63;            // same-XCD neighbors share tn (B-panel)
  const int tid = threadIdx.x;
  const int wave = tid >> 6, lane = tid & 63;
  const int wm = wave >> 1, wn = wave & 1;
  const int l15 = lane & 15, lhi = lane >> 4;
  // staging geometry: issue i covers LDS elems i*2048 + wave*512 + lane*8
  const int srow = wave * 16 + (lane >> 2);      // + i*64
  const int scol = (lane & 3) * 8;
  f32x4 acc[4][4] = {};

  for (int k0 = 0; k0 < 512; k0 += 32) {
    #pragma unroll
    for (int i = 0; i < 2; ++i) {
      const unsigned short* gA = A  + (size_t)(tm * 128 + i * 64 + srow) * 512 + k0 + scol;
      const unsigned short* gB = Bw + (size_t)(tn * 128 + i * 64 + srow) * 512 + k0 + scol;
      __builtin_amdgcn_global_load_lds((glob_cv*)gA, (lds_v*)(As + i * 2048 + wave * 512), 16, 0, 0);
      __builtin_amdgcn_global_load_lds((glob_cv*)gB, (lds_v*)(Bs + i * 2048 + wave * 512), 16, 0, 0);
    }
    __syncthreads();
    sh8 af[4], bfr[4];
    #pragma unroll
    for (int mi = 0; mi < 4; ++mi)
      af[mi] = *(const sh8*)(As + (wm * 64 + mi * 16 + l15) * 32 + lhi * 8);
    #pragma unroll
    for (int ni = 0; ni < 4; ++ni)
      bfr[ni] = *(const sh8*)(Bs + (wn * 64 + ni * 16 + l15) * 32 + lhi * 8);
    #pragma unroll
    for (int mi = 0; mi < 4; ++mi)
      #pragma unroll
      for (int ni = 0; ni < 4; ++ni)
        acc[mi][ni] = __builtin_amdgcn_mfma_f32_16x16x32_bf16(af[mi], bfr[ni], acc[mi][ni], 0, 0, 0);
    __syncthreads();
  }

  #pragma unroll
  for (int ni = 0; ni < 4; ++ni) {
    const int col = tn * 128 + wn * 64 + ni * 16 + l15;
    const float bv = bias[col];
    #pragma unroll
    for (int mi = 0; mi < 4; ++mi) {
      const int row0 = tm * 128 + wm * 64 + mi * 16 + lhi * 4;
      #pragma unroll
      for (int q = 0; q < 4; ++q)
        Y[(size_t)(row0 + q) * VSZ + col] = acc[mi][ni][q] + bv;
    }
  }
}

// ---------------- fallback out GEMM (r12): f32 B with in-kernel conversion --------------------
__global__ __launch_bounds__(256) void out_gemm_kernel(
    const unsigned short* __restrict__ A,  // 8192 x 512 bf16
    const float* __restrict__ Bw,          // 32000 x 512 f32
    const float* __restrict__ bias,        // 32000
    float* __restrict__ Y)                 // 8192 x 32000
{
  __shared__ unsigned short As[128 * 32];
  __shared__ unsigned short Bs[128 * 32];
  const int bid = blockIdx.x;
  const int s  = (bid & 7) * 2000 + (bid >> 3);
  const int tn = s >> 6, tm = s & 63;
  const int tid = threadIdx.x;
  const int wave = tid >> 6, lane = tid & 63;
  const int wm = wave >> 1, wn = wave & 1;
  const int l15 = lane & 15, lhi = lane >> 4;
  f32x4 acc[4][4] = {};

  for (int k0 = 0; k0 < 512; k0 += 32) {
    #pragma unroll
    for (int it = 0; it < 2; ++it) {
      const int ss  = tid + it * 256;
      const int row = ss >> 2;
      const int c8  = (ss & 3) << 3;
      *(uint4*)(As + row * 32 + c8) =
          *(const uint4*)(A + (size_t)(tm * 128 + row) * 512 + k0 + c8);
      const float4 b0 = *(const float4*)(Bw + (size_t)(tn * 128 + row) * 512 + k0 + c8);
      const float4 b1 = *(const float4*)(Bw + (size_t)(tn * 128 + row) * 512 + k0 + c8 + 4);
      union { unsigned short h[8]; uint4 u; } cv;
      cv.h[0] = f2bf(b0.x); cv.h[1] = f2bf(b0.y); cv.h[2] = f2bf(b0.z); cv.h[3] = f2bf(b0.w);
      cv.h[4] = f2bf(b1.x); cv.h[5] = f2bf(b1.y); cv.h[6] = f2bf(b1.z); cv.h[7] = f2bf(b1.w);
      *(uint4*)(Bs + row * 32 + c8) = cv.u;
    }
    __syncthreads();
    sh8 af[4], bfr[4];
    #pragma unroll
    for (int mi = 0; mi < 4; ++mi)
      af[mi] = *(const sh8*)(As + (wm * 64 + mi * 16 + l15) * 32 + lhi * 8);
    #pragma unroll
    for (int ni = 0; ni < 4; ++ni)
      bfr[ni] = *(const sh8*)(Bs + (wn * 64 + ni * 16 + l15) * 32 + lhi * 8);
    #pragma unroll
    for (int mi = 0; mi < 4; ++mi)
      #pragma unroll
      for (int ni = 0; ni < 4; ++ni)
        acc[mi][ni] = __builtin_amdgcn_mfma_f32_16x16x32_bf16(af[mi], bfr[ni], acc[mi][ni], 0, 0, 0);
    __syncthreads();
  }

  #pragma unroll
  for (int ni = 0; ni < 4; ++ni) {
    const int col = tn * 128 + wn * 64 + ni * 16 + l15;
    const float bv = bias[col];
    #pragma unroll
    for (int mi = 0; mi < 4; ++mi) {
      const int row0 = tm * 128 + wm * 64 + mi * 16 + lhi * 4;
      #pragma unroll
      for (int q = 0; q < 4; ++q)
        Y[(size_t)(row0 + q) * VSZ + col] = acc[mi][ni][q] + bv;
    }
  }
}

extern "C" void kernel_launch(void* const* d_in, const int* in_sizes, int n_in,
                              void* d_out, int out_size, void* d_ws, size_t ws_size,
                              hipStream_t stream)
{
  const int*   x   = (const int*)  d_in[0];
  const float* emb = (const float*)d_in[1];
  const float* Wr  = (const float*)d_in[2];
  const float* Br  = (const float*)d_in[3];
  const float* Wz  = (const float*)d_in[4];
  const float* Bz  = (const float*)d_in[5];
  const float* Wh  = (const float*)d_in[6];
  const float* Bh  = (const float*)d_in[7];
  const float* W   = (const float*)d_in[8];
  const float* bo  = (const float*)d_in[9];
  float* out = (float*)d_out;

  char* ws = (char*)d_ws;
  _Float16*       hF     = (_Float16*)(ws);                 //  64 KiB [64][512]
  _Float16*       uF     = (_Float16*)(ws + 65536);         //  64 KiB [64][512]
  unsigned*       flagsA = (unsigned*)(ws + 131072);        //  16 KiB (128 slots x 128B)
  unsigned*       flagsB = (unsigned*)(ws + 147456);        //  16 KiB
  unsigned short* Habf   = (unsigned short*)(ws + 163840);  //   8 MiB bf16 h history
  unsigned short* Wbf    = (unsigned short*)(ws + 163840 + 8388608);  // 32.7 MiB bf16 W
  const bool wide = ws_size >= (size_t)(163840 + 8388608 + (size_t)VSZ * HD * 2);

  // XG (pre-projection) overlays d_out; dead before out_gemm writes Y.
  float* XG   = out;                  // [8192][1536]
  float* outT = out + 262144000ll;    // hT.T region

  // zero hF, uF, flags (deterministic across graph replays)
  (void)hipMemsetAsync(ws, 0, 163840, stream);

  proj_kernel<<<dim3(12, 64), 256, 0, stream>>>(x, emb, Wr, Br, Wz, Bz, Wh, Bh, XG);
  if (wide) wconv_kernel<<<8000, 256, 0, stream>>>(W, Wbf);
  recur_kernel<<<NWG, 256, 0, stream>>>(XG, Wr, Wz, Wh, hF, uF, Habf, outT, flagsA, flagsB);
  if (wide)
    out_gemm_gll_kernel<<<16000, 256, 0, stream>>>(Habf, Wbf, bo, out);
  else
    out_gemm_kernel<<<16000, 256, 0, stream>>>(Habf, W, bo, out);
}